// Round 11
// baseline (342.976 us; speedup 1.0000x reference)
//
#include <hip/hip_runtime.h>
#include <climits>

#define NU_ 80000
#define NS_ 20000
#define NM_ 30000
#define UIN_ (NU_ + NS_)
#define DD 128
#define LL 32
#define RPB 64                                   // rows per bucket
#define NCH 256                                  // chunks per graph
#define NBUK_UI ((UIN_ + RPB - 1) / RPB)         // 1563
#define NBUK_MM ((NM_  + RPB - 1) / RPB)         // 469

#define F8_SCALE 512.0f
#define F8_INV   (1.0f / 512.0f)

typedef unsigned int       uint32;
typedef unsigned short     ushort_t;
typedef unsigned char      uchar_t;
typedef unsigned long long u64;
typedef float f32x2 __attribute__((ext_vector_type(2)));

__device__ __forceinline__ float bflo(uint32 u) { return __uint_as_float(u << 16); }
__device__ __forceinline__ float bfhi(uint32 u) { return __uint_as_float(u & 0xffff0000u); }
__device__ __forceinline__ uint32 f2bf(float f) {
    uint32 u = __float_as_uint(f);
    return (u + 0x7fffu + ((u >> 16) & 1u)) >> 16;   // RNE
}
__device__ __forceinline__ uint32 pack2bf(float lo, float hi) {
    return f2bf(lo) | (f2bf(hi) << 16);
}

// ---- nontemporal stream helpers (single-use data: don't pollute L2) ------
__device__ __forceinline__ u64 ntload_u64(const void* p) {
    return __builtin_nontemporal_load((const u64*)p);
}
__device__ __forceinline__ uint2 ntload_u2(const uint2* p) {
    u64 t = __builtin_nontemporal_load((const u64*)p);
    return make_uint2((uint32)t, (uint32)(t >> 32));
}
__device__ __forceinline__ void ntstore_u2(uint2* p, uint2 v) {
    __builtin_nontemporal_store(((u64)v.y << 32) | (u64)v.x, (u64*)p);
}
__device__ __forceinline__ int   ntload_i(const int* p)   { return __builtin_nontemporal_load(p); }
__device__ __forceinline__ float ntload_f(const float* p) { return __builtin_nontemporal_load(p); }

// ---- OCP e4m3fn encode/decode (HW converts on gfx950, SW fallback) --------
__device__ __forceinline__ float dec1_f8(uint32 b) {
    uint32 em = b & 0x7fu;
    uint32 s  = (b & 0x80u) << 24;
    float vn = __uint_as_float(s | (((em >> 3) + 120u) << 23) | ((em & 7u) << 20));
    float vd = (float)(int)em * 0.001953125f;
    vd = (b & 0x80u) ? -vd : vd;
    return (em >= 8u) ? vn : vd;
}
__device__ __forceinline__ uint32 enc1_f8(float f) {
    uint32 u = __float_as_uint(f);
    uint32 s = (u >> 31) << 7;
    float a = fabsf(f);
    if (a >= 448.0f) return s | 0x7Eu;
    if (a < 0.015625f) {
        int m = (int)(a * 512.0f + 0.5f);
        return s | (uint32)m;
    }
    uint32 au = u & 0x7fffffffu;
    au += 0x7FFFFu + ((au >> 20) & 1u);
    uint32 em = (((au >> 23) - 120u) << 3) | ((au >> 20) & 7u);
    if (em >= 0x7Fu) em = 0x7Eu;
    return s | em;
}
__device__ __forceinline__ f32x2 dec2_f8(uint32 u) {   // bytes 0,1
#if __has_builtin(__builtin_amdgcn_cvt_pk_f32_fp8)
    return __builtin_amdgcn_cvt_pk_f32_fp8(u, false);
#else
    f32x2 r; r.x = dec1_f8(u & 0xffu); r.y = dec1_f8((u >> 8) & 0xffu); return r;
#endif
}
__device__ __forceinline__ f32x2 dec2_f8_hi(uint32 u) { // bytes 2,3
#if __has_builtin(__builtin_amdgcn_cvt_pk_f32_fp8)
    return __builtin_amdgcn_cvt_pk_f32_fp8(u, true);
#else
    f32x2 r; r.x = dec1_f8((u >> 16) & 0xffu); r.y = dec1_f8(u >> 24); return r;
#endif
}
__device__ __forceinline__ uint32 pack2f8(float lo, float hi) {
#if __has_builtin(__builtin_amdgcn_cvt_pk_fp8_f32)
    return (uint32)__builtin_amdgcn_cvt_pk_fp8_f32(lo, hi, 0, false) & 0xFFFFu;
#else
    return enc1_f8(lo) | (enc1_f8(hi) << 8);
#endif
}

// ---------------------------------------------------------------------------
// Fused conversion: both tables -> bf16 + scaled fp8 in one dispatch.
// ---------------------------------------------------------------------------
__global__ void convert_fused(const float* __restrict__ user_tbl,
                              const float* __restrict__ service_tbl,
                              const float* __restrict__ mashup_tbl,
                              uint32* __restrict__ ui_bf, ushort_t* __restrict__ ui_f8,
                              uint32* __restrict__ mash_bf, ushort_t* __restrict__ mash_f8) {
    const size_t P_UI = (size_t)UIN_ * 64;
    const size_t P_MM = (size_t)NM_ * 64;
    const size_t SPLIT = (size_t)NU_ * DD;
    size_t stride = (size_t)gridDim.x * blockDim.x;
    for (size_t i = (size_t)blockIdx.x * blockDim.x + threadIdx.x; i < P_UI + P_MM; i += stride) {
        if (i < P_UI) {
            size_t e = i * 2;
            const float* s = (e < SPLIT) ? (user_tbl + e) : (service_tbl + (e - SPLIT));
            u64 t = ntload_u64(s);
            float lo = __uint_as_float((uint32)t), hi = __uint_as_float((uint32)(t >> 32));
            ui_bf[i] = pack2bf(lo, hi);
            ui_f8[i] = (ushort_t)pack2f8(lo * F8_SCALE, hi * F8_SCALE);
        } else {
            size_t j = i - P_UI;
            u64 t = ntload_u64(mashup_tbl + j * 2);
            float lo = __uint_as_float((uint32)t), hi = __uint_as_float((uint32)(t >> 32));
            mash_bf[j] = pack2bf(lo, hi);
            mash_f8[j] = (ushort_t)pack2f8(lo * F8_SCALE, hi * F8_SCALE);
        }
    }
}

// ---------------------------------------------------------------------------
// Stage 1 (fused): per-chunk bucket histogram, bucket-major h[b*NCH + c].
// ---------------------------------------------------------------------------
__global__ __launch_bounds__(1024) void hist_fused(
    const int* __restrict__ rows_ui, int E_ui, int csz_ui, int* __restrict__ h_ui,
    const int* __restrict__ rows_mm, int E_mm, int csz_mm, int* __restrict__ h_mm) {
    __shared__ int hist[NBUK_UI];
    const int* rows; int E, csz, nbuk, c; int* h;
    if ((int)blockIdx.x < NCH) { rows = rows_ui; E = E_ui; csz = csz_ui; h = h_ui; nbuk = NBUK_UI; c = blockIdx.x; }
    else                       { rows = rows_mm; E = E_mm; csz = csz_mm; h = h_mm; nbuk = NBUK_MM; c = blockIdx.x - NCH; }
    for (int i = threadIdx.x; i < nbuk; i += 1024) hist[i] = 0;
    __syncthreads();
    const int lo = c * csz, hi = min(lo + csz, E);
    int i = lo + threadIdx.x;
    for (; i + 3 * 1024 < hi; i += 4 * 1024) {
        int r0 = ntload_i(rows + i);
        int r1 = ntload_i(rows + i + 1024);
        int r2 = ntload_i(rows + i + 2048);
        int r3 = ntload_i(rows + i + 3072);
        atomicAdd(&hist[r0 >> 6], 1);
        atomicAdd(&hist[r1 >> 6], 1);
        atomicAdd(&hist[r2 >> 6], 1);
        atomicAdd(&hist[r3 >> 6], 1);
    }
    for (; i < hi; i += 1024) atomicAdd(&hist[ntload_i(rows + i) >> 6], 1);
    __syncthreads();
    for (int b = threadIdx.x; b < nbuk; b += 1024)
        h[b * NCH + c] = hist[b];
}

// ---------------------------------------------------------------------------
// Stage 2 (fused): multi-block exclusive scan over both histogram arrays.
// ---------------------------------------------------------------------------
__global__ __launch_bounds__(256) void scan_blocksum_fused(
    const int* __restrict__ h_ui, int n_ui, int* __restrict__ bs_ui, int nb_ui,
    const int* __restrict__ h_mm, int n_mm, int* __restrict__ bs_mm) {
    __shared__ int red[256];
    const int* cnt; int n, b; int* bsum;
    if ((int)blockIdx.x < nb_ui) { cnt = h_ui; n = n_ui; bsum = bs_ui; b = blockIdx.x; }
    else                         { cnt = h_mm; n = n_mm; bsum = bs_mm; b = blockIdx.x - nb_ui; }
    int base = b * 1024 + threadIdx.x * 4;
    int s = 0;
    if (base + 3 < n) {
        int4 v = *reinterpret_cast<const int4*>(cnt + base);
        s = v.x + v.y + v.z + v.w;
    } else {
        for (int i = base; i < n && i < base + 4; ++i) s += cnt[i];
    }
    red[threadIdx.x] = s;
    __syncthreads();
    for (int off = 128; off >= 1; off >>= 1) {
        if (threadIdx.x < off) red[threadIdx.x] += red[threadIdx.x + off];
        __syncthreads();
    }
    if (threadIdx.x == 0) bsum[b] = red[0];
}

__global__ __launch_bounds__(256) void scan_final_fused(
    int* __restrict__ h_ui, int n_ui, const int* __restrict__ bs_ui, int nb_ui,
    int* __restrict__ s_ui,
    int* __restrict__ h_mm, int n_mm, const int* __restrict__ bs_mm,
    int* __restrict__ s_mm) {
    __shared__ int lds[256];
    __shared__ int blk_off_s;
    const int tid = threadIdx.x;
    int* cnt; int n, b; const int* bsum; int* row_ptr;
    if ((int)blockIdx.x < nb_ui) { cnt = h_ui; n = n_ui; bsum = bs_ui; row_ptr = s_ui; b = blockIdx.x; }
    else                         { cnt = h_mm; n = n_mm; bsum = bs_mm; row_ptr = s_mm; b = blockIdx.x - nb_ui; }

    int s = 0;
    for (int j = tid; j < b; j += 256) s += bsum[j];
    lds[tid] = s;
    __syncthreads();
    for (int off = 128; off >= 1; off >>= 1) {
        if (tid < off) lds[tid] += lds[tid + off];
        __syncthreads();
    }
    if (tid == 0) blk_off_s = lds[0];
    __syncthreads();
    const int blk_off = blk_off_s;

    int base = b * 1024 + tid * 4;
    int c0 = 0, c1 = 0, c2 = 0, c3 = 0;
    if (base + 3 < n) {
        int4 v = *reinterpret_cast<const int4*>(cnt + base);
        c0 = v.x; c1 = v.y; c2 = v.z; c3 = v.w;
    } else {
        if (base     < n) c0 = cnt[base];
        if (base + 1 < n) c1 = cnt[base + 1];
        if (base + 2 < n) c2 = cnt[base + 2];
        if (base + 3 < n) c3 = cnt[base + 3];
    }
    int tsum = c0 + c1 + c2 + c3;
    __syncthreads();
    lds[tid] = tsum;
    __syncthreads();
    for (int off = 1; off < 256; off <<= 1) {
        int v = (tid >= off) ? lds[tid - off] : 0;
        __syncthreads();
        lds[tid] += v;
        __syncthreads();
    }
    int p0 = blk_off + ((tid > 0) ? lds[tid - 1] : 0);
    int p1 = p0 + c0, p2 = p1 + c1, p3 = p2 + c2, p4 = p3 + c3;

    if (base     < n) { row_ptr[base]     = p0; if (base     == n - 1) row_ptr[n] = p1; }
    if (base + 1 < n) { row_ptr[base + 1] = p1; if (base + 1 == n - 1) row_ptr[n] = p2; }
    if (base + 2 < n) { row_ptr[base + 2] = p2; if (base + 2 == n - 1) row_ptr[n] = p3; }
    if (base + 3 < n) { row_ptr[base + 3] = p3; if (base + 3 == n - 1) row_ptr[n] = p4; }
}

// ---------------------------------------------------------------------------
// Stage 3 (fused): per-chunk scatter into bucket-grouped cvA (per graph).
// ---------------------------------------------------------------------------
__global__ __launch_bounds__(1024) void scatter_fused(
    const int* __restrict__ rows_ui, const int* __restrict__ cols_ui,
    const float* __restrict__ vals_ui, const int* __restrict__ s_ui,
    int E_ui, int csz_ui, uint2* __restrict__ cvA_ui,
    const int* __restrict__ rows_mm, const int* __restrict__ cols_mm,
    const float* __restrict__ vals_mm, const int* __restrict__ s_mm,
    int E_mm, int csz_mm, uint2* __restrict__ cvA_mm) {
    __shared__ int cur[NBUK_UI];
    const int *rows, *cols; const float* vals; const int* s;
    int E, csz, nbuk, c; uint2* cvA;
    if ((int)blockIdx.x < NCH) {
        rows = rows_ui; cols = cols_ui; vals = vals_ui; s = s_ui;
        E = E_ui; csz = csz_ui; nbuk = NBUK_UI; c = blockIdx.x; cvA = cvA_ui;
    } else {
        rows = rows_mm; cols = cols_mm; vals = vals_mm; s = s_mm;
        E = E_mm; csz = csz_mm; nbuk = NBUK_MM; c = blockIdx.x - NCH; cvA = cvA_mm;
    }
    for (int b = threadIdx.x; b < nbuk; b += 1024) cur[b] = s[b * NCH + c];
    __syncthreads();
    const int lo = c * csz, hi = min(lo + csz, E);
    int i = lo + threadIdx.x;
    for (; i + 3 * 1024 < hi; i += 4 * 1024) {
        int   r0 = ntload_i(rows + i),        r1 = ntload_i(rows + i + 1024);
        int   r2 = ntload_i(rows + i + 2048), r3 = ntload_i(rows + i + 3072);
        int   q0 = ntload_i(cols + i),        q1 = ntload_i(cols + i + 1024);
        int   q2 = ntload_i(cols + i + 2048), q3 = ntload_i(cols + i + 3072);
        float v0 = ntload_f(vals + i),        v1 = ntload_f(vals + i + 1024);
        float v2 = ntload_f(vals + i + 2048), v3 = ntload_f(vals + i + 3072);
        int p0 = atomicAdd(&cur[r0 >> 6], 1);
        int p1 = atomicAdd(&cur[r1 >> 6], 1);
        int p2 = atomicAdd(&cur[r2 >> 6], 1);
        int p3 = atomicAdd(&cur[r3 >> 6], 1);
        ntstore_u2(cvA + p0, make_uint2((uint32)q0 | ((uint32)(r0 & 63) << 25), __float_as_uint(v0)));
        ntstore_u2(cvA + p1, make_uint2((uint32)q1 | ((uint32)(r1 & 63) << 25), __float_as_uint(v1)));
        ntstore_u2(cvA + p2, make_uint2((uint32)q2 | ((uint32)(r2 & 63) << 25), __float_as_uint(v2)));
        ntstore_u2(cvA + p3, make_uint2((uint32)q3 | ((uint32)(r3 & 63) << 25), __float_as_uint(v3)));
    }
    for (; i < hi; i += 1024) {
        int r = ntload_i(rows + i);
        int pos = atomicAdd(&cur[r >> 6], 1);
        ntstore_u2(cvA + pos, make_uint2((uint32)ntload_i(cols + i) | ((uint32)(r & 63) << 25),
                                         __float_as_uint(ntload_f(vals + i))));
    }
}

// ---------------------------------------------------------------------------
// Stage 4 (fused): exact per-row sort within each bucket (both graphs).
// ---------------------------------------------------------------------------
__device__ __forceinline__ void sort_one_bucket(
    const uint2* __restrict__ cvA, const int* __restrict__ s,
    uint2* __restrict__ cvB, int* __restrict__ row_ptr, int nrows, int b,
    int* cnt, int* cur) {
    const int tid  = threadIdx.x;
    const int base = s[b * NCH];
    const int endb = s[(b + 1) * NCH];

    if (tid < RPB) cnt[tid] = 0;
    __syncthreads();
    for (int i = base + tid; i < endb; i += 256)
        atomicAdd(&cnt[ntload_u2(cvA + i).x >> 25], 1);
    __syncthreads();
    if (tid < 64) {
        int c = cnt[tid];
        int x = c;
        #pragma unroll
        for (int off = 1; off < 64; off <<= 1) {
            int v = __shfl_up(x, off);
            if (tid >= off) x += v;
        }
        int excl = base + x - c;
        cur[tid] = excl;
        int grow = b * RPB + tid;
        if (grow <= nrows) row_ptr[grow] = excl;
    }
    __syncthreads();
    for (int i = base + tid; i < endb; i += 256) {
        uint2 e = ntload_u2(cvA + i);
        int rl  = (int)(e.x >> 25);
        int pos = atomicAdd(&cur[rl], 1);
        ntstore_u2(cvB + pos, make_uint2(e.x & 0x1FFFFFFu, e.y));
    }
}

__global__ __launch_bounds__(256) void sort_fused(
    const uint2* __restrict__ cvA_ui, const int* __restrict__ s_ui,
    uint2* __restrict__ cvB_ui, int* __restrict__ rp_ui,
    const uint2* __restrict__ cvA_mm, const int* __restrict__ s_mm,
    uint2* __restrict__ cvB_mm, int* __restrict__ rp_mm) {
    __shared__ int cnt[RPB];
    __shared__ int cur[RPB];
    if ((int)blockIdx.x < NBUK_UI)
        sort_one_bucket(cvA_ui, s_ui, cvB_ui, rp_ui, UIN_, blockIdx.x, cnt, cur);
    else
        sort_one_bucket(cvA_mm, s_mm, cvB_mm, rp_mm, NM_, blockIdx.x - NBUK_UI, cnt, cur);
}

// ---------------------------------------------------------------------------
// Pull SpMM row body — quarter-wave edges, predicated 4-slot batch:
// every quarter issues ALL its (<=4 per trip) cv loads then gathers under
// exec masks -> a row with deg<=16 completes in ONE memory round-trip.
// Masked slots have p.y==0 -> v=0 -> zero contribution.
// cv/orig/hprev are nontemporal (single-use streams); table x stays cached.
// ---------------------------------------------------------------------------
template <int MODE>
__device__ __forceinline__ void pull_row(
    const int wid, const int lane,
    const int* __restrict__ row_ptr, const uint2* __restrict__ cv,
    const uchar_t* __restrict__ x, const float* __restrict__ d_inv,
    const uint32* __restrict__ orig_bf, const uchar_t* __restrict__ hprev_f8,
    void* __restrict__ out)
{
    const int q    = lane >> 4;
    const int ql   = lane & 15;
    const int beg  = row_ptr[wid];
    const int end  = row_ptr[wid + 1];
    const int boff = ql << 3;

    float a0 = 0.f, a1 = 0.f, a2 = 0.f, a3 = 0.f;
    float a4 = 0.f, a5 = 0.f, a6 = 0.f, a7 = 0.f;

    for (int e = beg + q; e < end; e += 16) {
        const bool b1 = e + 4 < end, b2 = e + 8 < end, b3 = e + 12 < end;
        uint2 p0 = ntload_u2(cv + e);
        uint2 p1 = make_uint2(0u, 0u), p2 = make_uint2(0u, 0u), p3 = make_uint2(0u, 0u);
        if (b1) p1 = ntload_u2(cv + e + 4);
        if (b2) p2 = ntload_u2(cv + e + 8);
        if (b3) p3 = ntload_u2(cv + e + 12);
        uint2 g0 = *reinterpret_cast<const uint2*>(x + (((size_t)p0.x) << 7) + boff);
        uint2 g1 = make_uint2(0u, 0u), g2 = make_uint2(0u, 0u), g3 = make_uint2(0u, 0u);
        if (b1) g1 = *reinterpret_cast<const uint2*>(x + (((size_t)p1.x) << 7) + boff);
        if (b2) g2 = *reinterpret_cast<const uint2*>(x + (((size_t)p2.x) << 7) + boff);
        if (b3) g3 = *reinterpret_cast<const uint2*>(x + (((size_t)p3.x) << 7) + boff);
        float v0 = __uint_as_float(p0.y), v1 = __uint_as_float(p1.y);
        float v2 = __uint_as_float(p2.y), v3 = __uint_as_float(p3.y);
        {
            f32x2 d0 = dec2_f8(g0.x), d1 = dec2_f8_hi(g0.x);
            f32x2 d2 = dec2_f8(g0.y), d3 = dec2_f8_hi(g0.y);
            a0 += v0 * d0.x; a1 += v0 * d0.y; a2 += v0 * d1.x; a3 += v0 * d1.y;
            a4 += v0 * d2.x; a5 += v0 * d2.y; a6 += v0 * d3.x; a7 += v0 * d3.y;
        }
        {
            f32x2 d0 = dec2_f8(g1.x), d1 = dec2_f8_hi(g1.x);
            f32x2 d2 = dec2_f8(g1.y), d3 = dec2_f8_hi(g1.y);
            a0 += v1 * d0.x; a1 += v1 * d0.y; a2 += v1 * d1.x; a3 += v1 * d1.y;
            a4 += v1 * d2.x; a5 += v1 * d2.y; a6 += v1 * d3.x; a7 += v1 * d3.y;
        }
        {
            f32x2 d0 = dec2_f8(g2.x), d1 = dec2_f8_hi(g2.x);
            f32x2 d2 = dec2_f8(g2.y), d3 = dec2_f8_hi(g2.y);
            a0 += v2 * d0.x; a1 += v2 * d0.y; a2 += v2 * d1.x; a3 += v2 * d1.y;
            a4 += v2 * d2.x; a5 += v2 * d2.y; a6 += v2 * d3.x; a7 += v2 * d3.y;
        }
        {
            f32x2 d0 = dec2_f8(g3.x), d1 = dec2_f8_hi(g3.x);
            f32x2 d2 = dec2_f8(g3.y), d3 = dec2_f8_hi(g3.y);
            a0 += v3 * d0.x; a1 += v3 * d0.y; a2 += v3 * d1.x; a3 += v3 * d1.y;
            a4 += v3 * d2.x; a5 += v3 * d2.y; a6 += v3 * d3.x; a7 += v3 * d3.y;
        }
    }

    a0 += __shfl_xor(a0, 16); a0 += __shfl_xor(a0, 32);
    a1 += __shfl_xor(a1, 16); a1 += __shfl_xor(a1, 32);
    a2 += __shfl_xor(a2, 16); a2 += __shfl_xor(a2, 32);
    a3 += __shfl_xor(a3, 16); a3 += __shfl_xor(a3, 32);
    a4 += __shfl_xor(a4, 16); a4 += __shfl_xor(a4, 32);
    a5 += __shfl_xor(a5, 16); a5 += __shfl_xor(a5, 32);
    a6 += __shfl_xor(a6, 16); a6 += __shfl_xor(a6, 32);
    a7 += __shfl_xor(a7, 16); a7 += __shfl_xor(a7, 32);

    if (lane < 16) {
        if (MODE & 1) {
            float s = d_inv[wid];
            a0 *= s; a1 *= s; a2 *= s; a3 *= s;
            a4 *= s; a5 *= s; a6 *= s; a7 *= s;
        }
        if (MODE & 2) {
            const float inv3 = 1.0f / 3.0f;
            const u64* op = (const u64*)(orig_bf + (size_t)wid * 64 + (ql << 2));
            u64 o01 = ntload_u64(op);
            u64 o23 = ntload_u64(op + 1);
            u64 hp64 = ntload_u64(hprev_f8 + (((size_t)wid) << 7) + boff);
            uint32 hpx = (uint32)hp64, hpy = (uint32)(hp64 >> 32);
            f32x2 h0 = dec2_f8(hpx), h1 = dec2_f8_hi(hpx);
            f32x2 h2 = dec2_f8(hpy), h3 = dec2_f8_hi(hpy);
            uint4 r;
            r.x = pack2bf((bflo((uint32)o01)         + (h0.x + a0) * F8_INV) * inv3,
                          (bfhi((uint32)o01)         + (h0.y + a1) * F8_INV) * inv3);
            r.y = pack2bf((bflo((uint32)(o01 >> 32)) + (h1.x + a2) * F8_INV) * inv3,
                          (bfhi((uint32)(o01 >> 32)) + (h1.y + a3) * F8_INV) * inv3);
            r.z = pack2bf((bflo((uint32)o23)         + (h2.x + a4) * F8_INV) * inv3,
                          (bfhi((uint32)o23)         + (h2.y + a5) * F8_INV) * inv3);
            r.w = pack2bf((bflo((uint32)(o23 >> 32)) + (h3.x + a6) * F8_INV) * inv3,
                          (bfhi((uint32)(o23 >> 32)) + (h3.y + a7) * F8_INV) * inv3);
            *reinterpret_cast<uint4*>(reinterpret_cast<uint32*>(out) + (size_t)wid * 64 + (ql << 2)) = r;
        } else {
            uint2 r;
            r.x = pack2f8(a0, a1) | (pack2f8(a2, a3) << 16);
            r.y = pack2f8(a4, a5) | (pack2f8(a6, a7) << 16);
            *reinterpret_cast<uint2*>((uchar_t*)out + (((size_t)wid) << 7) + boff) = r;
        }
    }
}

// ---- unfused pull kernels (L2 purity per graph) ---------------------------
__global__ __launch_bounds__(256) void pull_ui_l1(
    const int* __restrict__ rp, const uint2* __restrict__ cv,
    const uchar_t* __restrict__ x, uchar_t* __restrict__ out) {
    const int lane = threadIdx.x & 63;
    int wid = blockIdx.x * 4 + (threadIdx.x >> 6);
    if (wid < UIN_) pull_row<0>(wid, lane, rp, cv, x, nullptr, nullptr, nullptr, out);
}
__global__ __launch_bounds__(256) void pull_mm_l1(
    const int* __restrict__ rp, const uint2* __restrict__ cv,
    const uchar_t* __restrict__ x, const float* __restrict__ d_inv,
    uchar_t* __restrict__ out) {
    const int lane = threadIdx.x & 63;
    int wid = blockIdx.x * 4 + (threadIdx.x >> 6);
    if (wid < NM_) pull_row<1>(wid, lane, rp, cv, x, d_inv, nullptr, nullptr, out);
}
__global__ __launch_bounds__(256) void pull_ui_l2(
    const int* __restrict__ rp, const uint2* __restrict__ cv,
    const uchar_t* __restrict__ h1, const uint32* __restrict__ orig_bf,
    uint32* __restrict__ out) {
    const int lane = threadIdx.x & 63;
    int wid = blockIdx.x * 4 + (threadIdx.x >> 6);
    if (wid < UIN_) pull_row<2>(wid, lane, rp, cv, h1, nullptr, orig_bf, h1, out);
}
__global__ __launch_bounds__(256) void pull_mm_l2(
    const int* __restrict__ rp, const uint2* __restrict__ cv,
    const uchar_t* __restrict__ m1, const float* __restrict__ d_inv,
    const uint32* __restrict__ orig_bf, uint32* __restrict__ out) {
    const int lane = threadIdx.x & 63;
    int wid = blockIdx.x * 4 + (threadIdx.x >> 6);
    if (wid < NM_) pull_row<3>(wid, lane, rp, cv, m1, d_inv, orig_bf, m1, out);
}

// ---------------------------------------------------------------------------
// Attention + prediction tail: one block (512 threads) per batch element.
// ---------------------------------------------------------------------------
__global__ __launch_bounds__(512) void attn_pred_kernel(
    const int* __restrict__ mashup_inputs, const int* __restrict__ service_inputs,
    const int* __restrict__ member_masked, const float* __restrict__ mask,
    const uint32* __restrict__ ui_final, const uint32* __restrict__ mash_final,
    const float* __restrict__ att_w1, const float* __restrict__ att_b1,
    const float* __restrict__ att_w2, const float* __restrict__ att_b2,
    const float* __restrict__ pred_w1, const float* __restrict__ pred_b1,
    const float* __restrict__ pred_w2, const float* __restrict__ pred_b2,
    float* __restrict__ out)
{
    const int b   = blockIdx.x;
    const int tid = threadIdx.x;

    __shared__ float mem_lds[LL * 129];
    __shared__ float svc_lds[DD];
    __shared__ float mash_lds[DD];
    __shared__ float w1_lds[2 * DD * 16];
    __shared__ float hdnw_lds[LL * 16];
    __shared__ float wt_lds[LL];
    __shared__ float new_lds[3 * DD];
    __shared__ float hp_lds[8];
    __shared__ int   midx[LL];

    if (tid < LL) midx[tid] = member_masked[b * LL + tid];
    for (int i = tid; i < 2 * DD * 16; i += 512) w1_lds[i] = att_w1[i];
    if (tid < 64) {
        int sidx = service_inputs[b];
        uint32 u = ui_final[(size_t)(NU_ + sidx) * 64 + tid];
        svc_lds[tid * 2]     = bflo(u);
        svc_lds[tid * 2 + 1] = bfhi(u);
    } else if (tid >= 448) {
        int t  = tid - 448;
        int mi = mashup_inputs[b];
        uint32 u = mash_final[(size_t)mi * 64 + t];
        mash_lds[t * 2]     = bflo(u);
        mash_lds[t * 2 + 1] = bfhi(u);
    }
    __syncthreads();

    for (int i = tid; i < LL * 64; i += 512) {
        int l = i >> 6, dp = (i & 63) * 2;
        uint32 u = ui_final[(size_t)midx[l] * 64 + (i & 63)];
        mem_lds[l * 129 + dp]     = bflo(u);
        mem_lds[l * 129 + dp + 1] = bfhi(u);
    }
    __syncthreads();

    {
        int l = tid >> 4, j = tid & 15;
        float acc = att_b1[j];
        const float* m = &mem_lds[l * 129];
        #pragma unroll 4
        for (int k = 0; k < DD; ++k) acc += m[k] * w1_lds[k * 16 + j];
        #pragma unroll 4
        for (int k = 0; k < DD; ++k) acc += svc_lds[k] * w1_lds[(DD + k) * 16 + j];
        acc = fmaxf(acc, 0.0f);
        hdnw_lds[l * 16 + j] = acc * att_w2[j];
    }
    __syncthreads();

    if (tid < 64) {
        float s = -3.0e38f;
        if (tid < LL) {
            s = att_b2[0];
            for (int j = 0; j < 16; ++j) s += hdnw_lds[tid * 16 + j];
            if (mask[b * LL + tid] > 0.0f) s = -1.0e9f;
        }
        float mx = s;
        for (int off = 16; off >= 1; off >>= 1) mx = fmaxf(mx, __shfl_xor(mx, off));
        float ex = (tid < LL) ? __expf(s - mx) : 0.0f;
        float sum = ex;
        for (int off = 16; off >= 1; off >>= 1) sum += __shfl_xor(sum, off);
        if (tid < LL) wt_lds[tid] = ex / sum;
    }
    __syncthreads();

    if (tid < DD) {
        float g = 0.0f;
        #pragma unroll 4
        for (int l = 0; l < LL; ++l) g += wt_lds[l] * mem_lds[l * 129 + tid];
        float me = g + mash_lds[tid];
        float sv = svc_lds[tid];
        new_lds[tid]          = me * sv;
        new_lds[DD + tid]     = me;
        new_lds[2 * DD + tid] = sv;
    }
    __syncthreads();

    if (tid < 8) {
        float acc = pred_b1[tid];
        for (int k = 0; k < 3 * DD; ++k) acc += new_lds[k] * pred_w1[k * 8 + tid];
        acc = fmaxf(acc, 0.0f);
        hp_lds[tid] = acc * pred_w2[tid];
    }
    __syncthreads();

    if (tid == 0) {
        float z = pred_b2[0];
        for (int j = 0; j < 8; ++j) z += hp_lds[j];
        out[b] = 1.0f / (1.0f + __expf(-z));
    }
}

// ---------------------------------------------------------------------------
extern "C" void kernel_launch(void* const* d_in, const int* in_sizes, int n_in,
                              void* d_out, int out_size, void* d_ws, size_t ws_size,
                              hipStream_t stream) {
    const int*   mashup_inputs  = (const int*)  d_in[0];
    const int*   service_inputs = (const int*)  d_in[1];
    const int*   member_masked  = (const int*)  d_in[2];
    const float* mask           = (const float*)d_in[3];
    const int*   adj_rows       = (const int*)  d_in[4];
    const int*   adj_cols       = (const int*)  d_in[5];
    const float* adj_vals       = (const float*)d_in[6];
    const int*   A_rows         = (const int*)  d_in[7];
    const int*   A_cols         = (const int*)  d_in[8];
    const float* A_vals         = (const float*)d_in[9];
    const float* d_inv          = (const float*)d_in[10];
    const float* user_tbl       = (const float*)d_in[11];
    const float* service_tbl    = (const float*)d_in[12];
    const float* mashup_tbl     = (const float*)d_in[13];
    const float* att_w1         = (const float*)d_in[14];
    const float* att_b1         = (const float*)d_in[15];
    const float* att_w2         = (const float*)d_in[16];
    const float* att_b2         = (const float*)d_in[17];
    const float* pred_w1        = (const float*)d_in[18];
    const float* pred_b1        = (const float*)d_in[19];
    const float* pred_w2        = (const float*)d_in[20];
    const float* pred_b2        = (const float*)d_in[21];

    const int E_ui = in_sizes[4];
    const int E_mm = in_sizes[7];
    const int B    = in_sizes[0];

    const int N_UI2  = NBUK_UI * NCH;              // 400128
    const int N_MM2  = NBUK_MM * NCH;              // 120064
    const int NB_UI  = (N_UI2 + 1023) / 1024;      // 391
    const int NB_MM  = (N_MM2 + 1023) / 1024;      // 118
    const int csz_ui = (E_ui + NCH - 1) / NCH;
    const int csz_mm = (E_mm + NCH - 1) / NCH;

    // ---- workspace layout (UI and MM regions fully disjoint) ----
    uint2*   cvA_ui  = (uint2*)d_ws;                           // E_ui
    uint2*   cvA_mm  = cvA_ui + E_ui;                          // E_mm
    uint2*   cvB_ui  = cvA_mm + E_mm;                          // E_ui
    uint2*   cvB_mm  = cvB_ui + E_ui;                          // E_mm
    int*     h_ui    = (int*)(cvB_mm + E_mm);                  // N_UI2
    int*     s_ui    = h_ui + N_UI2;                           // N_UI2+1 (+pad)
    int*     h_mm    = s_ui + N_UI2 + 4;                       // N_MM2
    int*     s_mm    = h_mm + N_MM2;                           // N_MM2+1 (+pad)
    int*     bs_ui   = s_mm + N_MM2 + 4;                       // 512
    int*     bs_mm   = bs_ui + 512;                            // 128
    int*     rp_ui   = bs_mm + 128;                            // UIN_+1 (+pad)
    int*     rp_mm   = rp_ui + UIN_ + 4;                       // NM_+1 (+pad)
    uint32*  ui_bf   = (uint32*)(rp_mm + NM_ + 4);             // UIN*64  (bf16 pairs)
    uint32*  mash_bf = ui_bf + (size_t)UIN_ * 64;              // NM*64
    uint32*  h2      = mash_bf + (size_t)NM_ * 64;             // UIN*64  (ui_final, bf16)
    uint32*  m2      = h2 + (size_t)UIN_ * 64;                 // NM*64   (mash_final, bf16)
    uchar_t* ui_f8   = (uchar_t*)(m2 + (size_t)NM_ * 64);      // UIN*128 (scaled fp8)
    uchar_t* h1_f8   = ui_f8 + (size_t)UIN_ * DD;              // UIN*128
    uchar_t* mash_f8 = h1_f8 + (size_t)UIN_ * DD;              // NM*128
    uchar_t* m1_f8   = mash_f8 + (size_t)NM_ * DD;             // NM*128

    // ---- 1: table conversion (bf16 + scaled fp8, both tables) ----
    convert_fused<<<2048, 256, 0, stream>>>(user_tbl, service_tbl, mashup_tbl,
                                            ui_bf, (ushort_t*)ui_f8,
                                            mash_bf, (ushort_t*)mash_f8);

    // ---- 2-6: fused edge build (hist -> scan -> scatter -> sort) ----
    hist_fused<<<2 * NCH, 1024, 0, stream>>>(adj_rows, E_ui, csz_ui, h_ui,
                                             A_rows, E_mm, csz_mm, h_mm);
    scan_blocksum_fused<<<NB_UI + NB_MM, 256, 0, stream>>>(h_ui, N_UI2, bs_ui, NB_UI,
                                                           h_mm, N_MM2, bs_mm);
    scan_final_fused<<<NB_UI + NB_MM, 256, 0, stream>>>(h_ui, N_UI2, bs_ui, NB_UI, s_ui,
                                                        h_mm, N_MM2, bs_mm, s_mm);
    scatter_fused<<<2 * NCH, 1024, 0, stream>>>(
        adj_rows, adj_cols, adj_vals, s_ui, E_ui, csz_ui, cvA_ui,
        A_rows, A_cols, A_vals, s_mm, E_mm, csz_mm, cvA_mm);
    sort_fused<<<NBUK_UI + NBUK_MM, 256, 0, stream>>>(
        cvA_ui, s_ui, cvB_ui, rp_ui,
        cvA_mm, s_mm, cvB_mm, rp_mm);

    // ---- 7-10: propagation layers (unfused: per-graph L2 purity) ----
    const int ui_blocks = (UIN_ + 3) / 4;   // 25000
    const int mm_blocks = (NM_ + 3) / 4;    // 7500
    pull_mm_l1<<<mm_blocks, 256, 0, stream>>>(rp_mm, cvB_mm, mash_f8, d_inv, m1_f8);
    pull_ui_l1<<<ui_blocks, 256, 0, stream>>>(rp_ui, cvB_ui, ui_f8, h1_f8);
    pull_mm_l2<<<mm_blocks, 256, 0, stream>>>(rp_mm, cvB_mm, m1_f8, d_inv, mash_bf, m2);
    pull_ui_l2<<<ui_blocks, 256, 0, stream>>>(rp_ui, cvB_ui, h1_f8, ui_bf, h2);

    // ---- 11: attention + prediction tail ----
    attn_pred_kernel<<<B, 512, 0, stream>>>(
        mashup_inputs, service_inputs, member_masked, mask,
        h2, m2,
        att_w1, att_b1, att_w2, att_b2,
        pred_w1, pred_b1, pred_w2, pred_b2,
        (float*)d_out);
}

// Round 12
// 256.073 us; speedup vs baseline: 1.3394x; 1.3394x over previous
//
#include <hip/hip_runtime.h>
#include <climits>

#define NU_ 80000
#define NS_ 20000
#define NM_ 30000
#define UIN_ (NU_ + NS_)
#define DD 128
#define LL 32
#define RPB 64                                   // rows per bucket
#define NCH 256                                  // chunks per graph
#define NBUK_UI ((UIN_ + RPB - 1) / RPB)         // 1563
#define NBUK_MM ((NM_  + RPB - 1) / RPB)         // 469

#define F8_SCALE 512.0f
#define F8_INV   (1.0f / 512.0f)

typedef unsigned int   uint32;
typedef unsigned short ushort_t;
typedef unsigned char  uchar_t;
typedef float f32x2 __attribute__((ext_vector_type(2)));

__device__ __forceinline__ float bflo(uint32 u) { return __uint_as_float(u << 16); }
__device__ __forceinline__ float bfhi(uint32 u) { return __uint_as_float(u & 0xffff0000u); }
__device__ __forceinline__ uint32 f2bf(float f) {
    uint32 u = __float_as_uint(f);
    return (u + 0x7fffu + ((u >> 16) & 1u)) >> 16;   // RNE
}
__device__ __forceinline__ uint32 pack2bf(float lo, float hi) {
    return f2bf(lo) | (f2bf(hi) << 16);
}

// ---- OCP e4m3fn encode/decode (HW converts on gfx950, SW fallback) --------
__device__ __forceinline__ float dec1_f8(uint32 b) {
    uint32 em = b & 0x7fu;
    uint32 s  = (b & 0x80u) << 24;
    float vn = __uint_as_float(s | (((em >> 3) + 120u) << 23) | ((em & 7u) << 20));
    float vd = (float)(int)em * 0.001953125f;
    vd = (b & 0x80u) ? -vd : vd;
    return (em >= 8u) ? vn : vd;
}
__device__ __forceinline__ uint32 enc1_f8(float f) {
    uint32 u = __float_as_uint(f);
    uint32 s = (u >> 31) << 7;
    float a = fabsf(f);
    if (a >= 448.0f) return s | 0x7Eu;
    if (a < 0.015625f) {
        int m = (int)(a * 512.0f + 0.5f);
        return s | (uint32)m;
    }
    uint32 au = u & 0x7fffffffu;
    au += 0x7FFFFu + ((au >> 20) & 1u);
    uint32 em = (((au >> 23) - 120u) << 3) | ((au >> 20) & 7u);
    if (em >= 0x7Fu) em = 0x7Eu;
    return s | em;
}
__device__ __forceinline__ f32x2 dec2_f8(uint32 u) {   // bytes 0,1
#if __has_builtin(__builtin_amdgcn_cvt_pk_f32_fp8)
    return __builtin_amdgcn_cvt_pk_f32_fp8(u, false);
#else
    f32x2 r; r.x = dec1_f8(u & 0xffu); r.y = dec1_f8((u >> 8) & 0xffu); return r;
#endif
}
__device__ __forceinline__ f32x2 dec2_f8_hi(uint32 u) { // bytes 2,3
#if __has_builtin(__builtin_amdgcn_cvt_pk_f32_fp8)
    return __builtin_amdgcn_cvt_pk_f32_fp8(u, true);
#else
    f32x2 r; r.x = dec1_f8((u >> 16) & 0xffu); r.y = dec1_f8(u >> 24); return r;
#endif
}
__device__ __forceinline__ uint32 pack2f8(float lo, float hi) {
#if __has_builtin(__builtin_amdgcn_cvt_pk_fp8_f32)
    return (uint32)__builtin_amdgcn_cvt_pk_fp8_f32(lo, hi, 0, false) & 0xFFFFu;
#else
    return enc1_f8(lo) | (enc1_f8(hi) << 8);
#endif
}

// ---------------------------------------------------------------------------
// Fused conversion: both tables -> bf16 + scaled fp8 in one dispatch.
// ---------------------------------------------------------------------------
__global__ void convert_fused(const float* __restrict__ user_tbl,
                              const float* __restrict__ service_tbl,
                              const float* __restrict__ mashup_tbl,
                              uint32* __restrict__ ui_bf, ushort_t* __restrict__ ui_f8,
                              uint32* __restrict__ mash_bf, ushort_t* __restrict__ mash_f8) {
    const size_t P_UI = (size_t)UIN_ * 64;
    const size_t P_MM = (size_t)NM_ * 64;
    const size_t SPLIT = (size_t)NU_ * DD;
    size_t stride = (size_t)gridDim.x * blockDim.x;
    for (size_t i = (size_t)blockIdx.x * blockDim.x + threadIdx.x; i < P_UI + P_MM; i += stride) {
        if (i < P_UI) {
            size_t e = i * 2;
            const float* s = (e < SPLIT) ? (user_tbl + e) : (service_tbl + (e - SPLIT));
            float2 v = *reinterpret_cast<const float2*>(s);
            ui_bf[i] = pack2bf(v.x, v.y);
            ui_f8[i] = (ushort_t)pack2f8(v.x * F8_SCALE, v.y * F8_SCALE);
        } else {
            size_t j = i - P_UI;
            float2 v = *reinterpret_cast<const float2*>(mashup_tbl + j * 2);
            mash_bf[j] = pack2bf(v.x, v.y);
            mash_f8[j] = (ushort_t)pack2f8(v.x * F8_SCALE, v.y * F8_SCALE);
        }
    }
}

// ---------------------------------------------------------------------------
// Stage 1 (fused): per-chunk bucket histogram, bucket-major h[b*NCH + c].
// ---------------------------------------------------------------------------
__global__ __launch_bounds__(1024) void hist_fused(
    const int* __restrict__ rows_ui, int E_ui, int csz_ui, int* __restrict__ h_ui,
    const int* __restrict__ rows_mm, int E_mm, int csz_mm, int* __restrict__ h_mm) {
    __shared__ int hist[NBUK_UI];
    const int* rows; int E, csz, nbuk, c; int* h;
    if ((int)blockIdx.x < NCH) { rows = rows_ui; E = E_ui; csz = csz_ui; h = h_ui; nbuk = NBUK_UI; c = blockIdx.x; }
    else                       { rows = rows_mm; E = E_mm; csz = csz_mm; h = h_mm; nbuk = NBUK_MM; c = blockIdx.x - NCH; }
    for (int i = threadIdx.x; i < nbuk; i += 1024) hist[i] = 0;
    __syncthreads();
    const int lo = c * csz, hi = min(lo + csz, E);
    int i = lo + threadIdx.x;
    for (; i + 3 * 1024 < hi; i += 4 * 1024) {
        int r0 = rows[i];
        int r1 = rows[i + 1024];
        int r2 = rows[i + 2048];
        int r3 = rows[i + 3072];
        atomicAdd(&hist[r0 >> 6], 1);
        atomicAdd(&hist[r1 >> 6], 1);
        atomicAdd(&hist[r2 >> 6], 1);
        atomicAdd(&hist[r3 >> 6], 1);
    }
    for (; i < hi; i += 1024) atomicAdd(&hist[rows[i] >> 6], 1);
    __syncthreads();
    for (int b = threadIdx.x; b < nbuk; b += 1024)
        h[b * NCH + c] = hist[b];
}

// ---------------------------------------------------------------------------
// Stage 2 (fused): multi-block exclusive scan over both histogram arrays.
// ---------------------------------------------------------------------------
__global__ __launch_bounds__(256) void scan_blocksum_fused(
    const int* __restrict__ h_ui, int n_ui, int* __restrict__ bs_ui, int nb_ui,
    const int* __restrict__ h_mm, int n_mm, int* __restrict__ bs_mm) {
    __shared__ int red[256];
    const int* cnt; int n, b; int* bsum;
    if ((int)blockIdx.x < nb_ui) { cnt = h_ui; n = n_ui; bsum = bs_ui; b = blockIdx.x; }
    else                         { cnt = h_mm; n = n_mm; bsum = bs_mm; b = blockIdx.x - nb_ui; }
    int base = b * 1024 + threadIdx.x * 4;
    int s = 0;
    if (base + 3 < n) {
        int4 v = *reinterpret_cast<const int4*>(cnt + base);
        s = v.x + v.y + v.z + v.w;
    } else {
        for (int i = base; i < n && i < base + 4; ++i) s += cnt[i];
    }
    red[threadIdx.x] = s;
    __syncthreads();
    for (int off = 128; off >= 1; off >>= 1) {
        if (threadIdx.x < off) red[threadIdx.x] += red[threadIdx.x + off];
        __syncthreads();
    }
    if (threadIdx.x == 0) bsum[b] = red[0];
}

__global__ __launch_bounds__(256) void scan_final_fused(
    int* __restrict__ h_ui, int n_ui, const int* __restrict__ bs_ui, int nb_ui,
    int* __restrict__ s_ui,
    int* __restrict__ h_mm, int n_mm, const int* __restrict__ bs_mm,
    int* __restrict__ s_mm) {
    __shared__ int lds[256];
    __shared__ int blk_off_s;
    const int tid = threadIdx.x;
    int* cnt; int n, b; const int* bsum; int* row_ptr;
    if ((int)blockIdx.x < nb_ui) { cnt = h_ui; n = n_ui; bsum = bs_ui; row_ptr = s_ui; b = blockIdx.x; }
    else                         { cnt = h_mm; n = n_mm; bsum = bs_mm; row_ptr = s_mm; b = blockIdx.x - nb_ui; }

    int s = 0;
    for (int j = tid; j < b; j += 256) s += bsum[j];
    lds[tid] = s;
    __syncthreads();
    for (int off = 128; off >= 1; off >>= 1) {
        if (tid < off) lds[tid] += lds[tid + off];
        __syncthreads();
    }
    if (tid == 0) blk_off_s = lds[0];
    __syncthreads();
    const int blk_off = blk_off_s;

    int base = b * 1024 + tid * 4;
    int c0 = 0, c1 = 0, c2 = 0, c3 = 0;
    if (base + 3 < n) {
        int4 v = *reinterpret_cast<const int4*>(cnt + base);
        c0 = v.x; c1 = v.y; c2 = v.z; c3 = v.w;
    } else {
        if (base     < n) c0 = cnt[base];
        if (base + 1 < n) c1 = cnt[base + 1];
        if (base + 2 < n) c2 = cnt[base + 2];
        if (base + 3 < n) c3 = cnt[base + 3];
    }
    int tsum = c0 + c1 + c2 + c3;
    __syncthreads();
    lds[tid] = tsum;
    __syncthreads();
    for (int off = 1; off < 256; off <<= 1) {
        int v = (tid >= off) ? lds[tid - off] : 0;
        __syncthreads();
        lds[tid] += v;
        __syncthreads();
    }
    int p0 = blk_off + ((tid > 0) ? lds[tid - 1] : 0);
    int p1 = p0 + c0, p2 = p1 + c1, p3 = p2 + c2, p4 = p3 + c3;

    if (base     < n) { row_ptr[base]     = p0; if (base     == n - 1) row_ptr[n] = p1; }
    if (base + 1 < n) { row_ptr[base + 1] = p1; if (base + 1 == n - 1) row_ptr[n] = p2; }
    if (base + 2 < n) { row_ptr[base + 2] = p2; if (base + 2 == n - 1) row_ptr[n] = p3; }
    if (base + 3 < n) { row_ptr[base + 3] = p3; if (base + 3 == n - 1) row_ptr[n] = p4; }
}

// ---------------------------------------------------------------------------
// Stage 3 (fused): per-chunk scatter into bucket-grouped cvA (per graph).
// Plain stores: temporally-local partial lines MERGE IN L2 (round-11 lesson:
// nontemporal stores here cause 3x write amplification).
// ---------------------------------------------------------------------------
__global__ __launch_bounds__(1024) void scatter_fused(
    const int* __restrict__ rows_ui, const int* __restrict__ cols_ui,
    const float* __restrict__ vals_ui, const int* __restrict__ s_ui,
    int E_ui, int csz_ui, uint2* __restrict__ cvA_ui,
    const int* __restrict__ rows_mm, const int* __restrict__ cols_mm,
    const float* __restrict__ vals_mm, const int* __restrict__ s_mm,
    int E_mm, int csz_mm, uint2* __restrict__ cvA_mm) {
    __shared__ int cur[NBUK_UI];
    const int *rows, *cols; const float* vals; const int* s;
    int E, csz, nbuk, c; uint2* cvA;
    if ((int)blockIdx.x < NCH) {
        rows = rows_ui; cols = cols_ui; vals = vals_ui; s = s_ui;
        E = E_ui; csz = csz_ui; nbuk = NBUK_UI; c = blockIdx.x; cvA = cvA_ui;
    } else {
        rows = rows_mm; cols = cols_mm; vals = vals_mm; s = s_mm;
        E = E_mm; csz = csz_mm; nbuk = NBUK_MM; c = blockIdx.x - NCH; cvA = cvA_mm;
    }
    for (int b = threadIdx.x; b < nbuk; b += 1024) cur[b] = s[b * NCH + c];
    __syncthreads();
    const int lo = c * csz, hi = min(lo + csz, E);
    int i = lo + threadIdx.x;
    for (; i + 3 * 1024 < hi; i += 4 * 1024) {
        int   r0 = rows[i],        r1 = rows[i + 1024];
        int   r2 = rows[i + 2048], r3 = rows[i + 3072];
        int   q0 = cols[i],        q1 = cols[i + 1024];
        int   q2 = cols[i + 2048], q3 = cols[i + 3072];
        float v0 = vals[i],        v1 = vals[i + 1024];
        float v2 = vals[i + 2048], v3 = vals[i + 3072];
        int p0 = atomicAdd(&cur[r0 >> 6], 1);
        int p1 = atomicAdd(&cur[r1 >> 6], 1);
        int p2 = atomicAdd(&cur[r2 >> 6], 1);
        int p3 = atomicAdd(&cur[r3 >> 6], 1);
        cvA[p0] = make_uint2((uint32)q0 | ((uint32)(r0 & 63) << 25), __float_as_uint(v0));
        cvA[p1] = make_uint2((uint32)q1 | ((uint32)(r1 & 63) << 25), __float_as_uint(v1));
        cvA[p2] = make_uint2((uint32)q2 | ((uint32)(r2 & 63) << 25), __float_as_uint(v2));
        cvA[p3] = make_uint2((uint32)q3 | ((uint32)(r3 & 63) << 25), __float_as_uint(v3));
    }
    for (; i < hi; i += 1024) {
        int r = rows[i];
        int pos = atomicAdd(&cur[r >> 6], 1);
        cvA[pos] = make_uint2((uint32)cols[i] | ((uint32)(r & 63) << 25),
                              __float_as_uint(vals[i]));
    }
}

// ---------------------------------------------------------------------------
// Stage 4 (fused): exact per-row sort within each bucket (both graphs).
// ---------------------------------------------------------------------------
__device__ __forceinline__ void sort_one_bucket(
    const uint2* __restrict__ cvA, const int* __restrict__ s,
    uint2* __restrict__ cvB, int* __restrict__ row_ptr, int nrows, int b,
    int* cnt, int* cur) {
    const int tid  = threadIdx.x;
    const int base = s[b * NCH];
    const int endb = s[(b + 1) * NCH];

    if (tid < RPB) cnt[tid] = 0;
    __syncthreads();
    for (int i = base + tid; i < endb; i += 256)
        atomicAdd(&cnt[cvA[i].x >> 25], 1);
    __syncthreads();
    if (tid < 64) {
        int c = cnt[tid];
        int x = c;
        #pragma unroll
        for (int off = 1; off < 64; off <<= 1) {
            int v = __shfl_up(x, off);
            if (tid >= off) x += v;
        }
        int excl = base + x - c;
        cur[tid] = excl;
        int grow = b * RPB + tid;
        if (grow <= nrows) row_ptr[grow] = excl;
    }
    __syncthreads();
    for (int i = base + tid; i < endb; i += 256) {
        uint2 e = cvA[i];
        int rl  = (int)(e.x >> 25);
        int pos = atomicAdd(&cur[rl], 1);
        cvB[pos] = make_uint2(e.x & 0x1FFFFFFu, e.y);
    }
}

__global__ __launch_bounds__(256) void sort_fused(
    const uint2* __restrict__ cvA_ui, const int* __restrict__ s_ui,
    uint2* __restrict__ cvB_ui, int* __restrict__ rp_ui,
    const uint2* __restrict__ cvA_mm, const int* __restrict__ s_mm,
    uint2* __restrict__ cvB_mm, int* __restrict__ rp_mm) {
    __shared__ int cnt[RPB];
    __shared__ int cur[RPB];
    if ((int)blockIdx.x < NBUK_UI)
        sort_one_bucket(cvA_ui, s_ui, cvB_ui, rp_ui, UIN_, blockIdx.x, cnt, cur);
    else
        sort_one_bucket(cvA_mm, s_mm, cvB_mm, rp_mm, NM_, blockIdx.x - NBUK_UI, cnt, cur);
}

// ---------------------------------------------------------------------------
// Pull SpMM row body — quarter-wave edges, 2-deep unroll (round-9 proven:
// 54.8 us on UI). Lane ql owns dims 8*ql..8*ql+7 (uint2 = 8 fp8 bytes).
// One gather instruction fetches 4 edges' rows; 8 edges in flight per wave.
// Epilogue: shfl_xor(16,32) cross-quarter reduce, lanes 0-15 write.
// MODE bit0: d_inv scale. MODE bit1: bf16 combine out; else fp8 (scaled) out.
// ---------------------------------------------------------------------------
template <int MODE>
__device__ __forceinline__ void pull_row(
    const int wid, const int lane,
    const int* __restrict__ row_ptr, const uint2* __restrict__ cv,
    const uchar_t* __restrict__ x, const float* __restrict__ d_inv,
    const uint32* __restrict__ orig_bf, const uchar_t* __restrict__ hprev_f8,
    void* __restrict__ out)
{
    const int q    = lane >> 4;
    const int ql   = lane & 15;
    const int beg  = row_ptr[wid];
    const int end  = row_ptr[wid + 1];
    const int boff = ql << 3;

    float a0 = 0.f, a1 = 0.f, a2 = 0.f, a3 = 0.f;
    float a4 = 0.f, a5 = 0.f, a6 = 0.f, a7 = 0.f;

    int e = beg + q;
    for (; e + 4 < end; e += 8) {
        uint2 pa = cv[e];
        uint2 pb = cv[e + 4];
        uint2 ga = *reinterpret_cast<const uint2*>(x + (((size_t)pa.x) << 7) + boff);
        uint2 gb = *reinterpret_cast<const uint2*>(x + (((size_t)pb.x) << 7) + boff);
        float va = __uint_as_float(pa.y);
        float vb = __uint_as_float(pb.y);
        f32x2 d0 = dec2_f8(ga.x), d1 = dec2_f8_hi(ga.x);
        f32x2 d2 = dec2_f8(ga.y), d3 = dec2_f8_hi(ga.y);
        a0 += va * d0.x; a1 += va * d0.y; a2 += va * d1.x; a3 += va * d1.y;
        a4 += va * d2.x; a5 += va * d2.y; a6 += va * d3.x; a7 += va * d3.y;
        f32x2 e0 = dec2_f8(gb.x), e1 = dec2_f8_hi(gb.x);
        f32x2 e2 = dec2_f8(gb.y), e3 = dec2_f8_hi(gb.y);
        a0 += vb * e0.x; a1 += vb * e0.y; a2 += vb * e1.x; a3 += vb * e1.y;
        a4 += vb * e2.x; a5 += vb * e2.y; a6 += vb * e3.x; a7 += vb * e3.y;
    }
    if (e < end) {
        uint2 pa = cv[e];
        uint2 ga = *reinterpret_cast<const uint2*>(x + (((size_t)pa.x) << 7) + boff);
        float va = __uint_as_float(pa.y);
        f32x2 d0 = dec2_f8(ga.x), d1 = dec2_f8_hi(ga.x);
        f32x2 d2 = dec2_f8(ga.y), d3 = dec2_f8_hi(ga.y);
        a0 += va * d0.x; a1 += va * d0.y; a2 += va * d1.x; a3 += va * d1.y;
        a4 += va * d2.x; a5 += va * d2.y; a6 += va * d3.x; a7 += va * d3.y;
    }

    a0 += __shfl_xor(a0, 16); a0 += __shfl_xor(a0, 32);
    a1 += __shfl_xor(a1, 16); a1 += __shfl_xor(a1, 32);
    a2 += __shfl_xor(a2, 16); a2 += __shfl_xor(a2, 32);
    a3 += __shfl_xor(a3, 16); a3 += __shfl_xor(a3, 32);
    a4 += __shfl_xor(a4, 16); a4 += __shfl_xor(a4, 32);
    a5 += __shfl_xor(a5, 16); a5 += __shfl_xor(a5, 32);
    a6 += __shfl_xor(a6, 16); a6 += __shfl_xor(a6, 32);
    a7 += __shfl_xor(a7, 16); a7 += __shfl_xor(a7, 32);

    if (lane < 16) {
        if (MODE & 1) {
            float s = d_inv[wid];
            a0 *= s; a1 *= s; a2 *= s; a3 *= s;
            a4 *= s; a5 *= s; a6 *= s; a7 *= s;
        }
        if (MODE & 2) {
            const float inv3 = 1.0f / 3.0f;
            uint4 o = *reinterpret_cast<const uint4*>(orig_bf + (size_t)wid * 64 + (ql << 2));
            uint2 hp = *reinterpret_cast<const uint2*>(hprev_f8 + (((size_t)wid) << 7) + boff);
            f32x2 h0 = dec2_f8(hp.x), h1 = dec2_f8_hi(hp.x);
            f32x2 h2 = dec2_f8(hp.y), h3 = dec2_f8_hi(hp.y);
            uint4 r;
            r.x = pack2bf((bflo(o.x) + (h0.x + a0) * F8_INV) * inv3,
                          (bfhi(o.x) + (h0.y + a1) * F8_INV) * inv3);
            r.y = pack2bf((bflo(o.y) + (h1.x + a2) * F8_INV) * inv3,
                          (bfhi(o.y) + (h1.y + a3) * F8_INV) * inv3);
            r.z = pack2bf((bflo(o.z) + (h2.x + a4) * F8_INV) * inv3,
                          (bfhi(o.z) + (h2.y + a5) * F8_INV) * inv3);
            r.w = pack2bf((bflo(o.w) + (h3.x + a6) * F8_INV) * inv3,
                          (bfhi(o.w) + (h3.y + a7) * F8_INV) * inv3);
            *reinterpret_cast<uint4*>(reinterpret_cast<uint32*>(out) + (size_t)wid * 64 + (ql << 2)) = r;
        } else {
            uint2 r;
            r.x = pack2f8(a0, a1) | (pack2f8(a2, a3) << 16);
            r.y = pack2f8(a4, a5) | (pack2f8(a6, a7) << 16);
            *reinterpret_cast<uint2*>((uchar_t*)out + (((size_t)wid) << 7) + boff) = r;
        }
    }
}

// ---- unfused pull kernels (per-graph L2 purity; round-10 lesson) ----------
__global__ __launch_bounds__(256) void pull_ui_l1(
    const int* __restrict__ rp, const uint2* __restrict__ cv,
    const uchar_t* __restrict__ x, uchar_t* __restrict__ out) {
    const int lane = threadIdx.x & 63;
    int wid = blockIdx.x * 4 + (threadIdx.x >> 6);
    if (wid < UIN_) pull_row<0>(wid, lane, rp, cv, x, nullptr, nullptr, nullptr, out);
}
__global__ __launch_bounds__(256) void pull_mm_l1(
    const int* __restrict__ rp, const uint2* __restrict__ cv,
    const uchar_t* __restrict__ x, const float* __restrict__ d_inv,
    uchar_t* __restrict__ out) {
    const int lane = threadIdx.x & 63;
    int wid = blockIdx.x * 4 + (threadIdx.x >> 6);
    if (wid < NM_) pull_row<1>(wid, lane, rp, cv, x, d_inv, nullptr, nullptr, out);
}
__global__ __launch_bounds__(256) void pull_ui_l2(
    const int* __restrict__ rp, const uint2* __restrict__ cv,
    const uchar_t* __restrict__ h1, const uint32* __restrict__ orig_bf,
    uint32* __restrict__ out) {
    const int lane = threadIdx.x & 63;
    int wid = blockIdx.x * 4 + (threadIdx.x >> 6);
    if (wid < UIN_) pull_row<2>(wid, lane, rp, cv, h1, nullptr, orig_bf, h1, out);
}
__global__ __launch_bounds__(256) void pull_mm_l2(
    const int* __restrict__ rp, const uint2* __restrict__ cv,
    const uchar_t* __restrict__ m1, const float* __restrict__ d_inv,
    const uint32* __restrict__ orig_bf, uint32* __restrict__ out) {
    const int lane = threadIdx.x & 63;
    int wid = blockIdx.x * 4 + (threadIdx.x >> 6);
    if (wid < NM_) pull_row<3>(wid, lane, rp, cv, m1, d_inv, orig_bf, m1, out);
}

// ---------------------------------------------------------------------------
// Attention + prediction tail: one block (512 threads) per batch element.
// ---------------------------------------------------------------------------
__global__ __launch_bounds__(512) void attn_pred_kernel(
    const int* __restrict__ mashup_inputs, const int* __restrict__ service_inputs,
    const int* __restrict__ member_masked, const float* __restrict__ mask,
    const uint32* __restrict__ ui_final, const uint32* __restrict__ mash_final,
    const float* __restrict__ att_w1, const float* __restrict__ att_b1,
    const float* __restrict__ att_w2, const float* __restrict__ att_b2,
    const float* __restrict__ pred_w1, const float* __restrict__ pred_b1,
    const float* __restrict__ pred_w2, const float* __restrict__ pred_b2,
    float* __restrict__ out)
{
    const int b   = blockIdx.x;
    const int tid = threadIdx.x;

    __shared__ float mem_lds[LL * 129];
    __shared__ float svc_lds[DD];
    __shared__ float mash_lds[DD];
    __shared__ float w1_lds[2 * DD * 16];
    __shared__ float hdnw_lds[LL * 16];
    __shared__ float wt_lds[LL];
    __shared__ float new_lds[3 * DD];
    __shared__ float hp_lds[8];
    __shared__ int   midx[LL];

    if (tid < LL) midx[tid] = member_masked[b * LL + tid];
    for (int i = tid; i < 2 * DD * 16; i += 512) w1_lds[i] = att_w1[i];
    if (tid < 64) {
        int sidx = service_inputs[b];
        uint32 u = ui_final[(size_t)(NU_ + sidx) * 64 + tid];
        svc_lds[tid * 2]     = bflo(u);
        svc_lds[tid * 2 + 1] = bfhi(u);
    } else if (tid >= 448) {
        int t  = tid - 448;
        int mi = mashup_inputs[b];
        uint32 u = mash_final[(size_t)mi * 64 + t];
        mash_lds[t * 2]     = bflo(u);
        mash_lds[t * 2 + 1] = bfhi(u);
    }
    __syncthreads();

    for (int i = tid; i < LL * 64; i += 512) {
        int l = i >> 6, dp = (i & 63) * 2;
        uint32 u = ui_final[(size_t)midx[l] * 64 + (i & 63)];
        mem_lds[l * 129 + dp]     = bflo(u);
        mem_lds[l * 129 + dp + 1] = bfhi(u);
    }
    __syncthreads();

    {
        int l = tid >> 4, j = tid & 15;
        float acc = att_b1[j];
        const float* m = &mem_lds[l * 129];
        #pragma unroll 4
        for (int k = 0; k < DD; ++k) acc += m[k] * w1_lds[k * 16 + j];
        #pragma unroll 4
        for (int k = 0; k < DD; ++k) acc += svc_lds[k] * w1_lds[(DD + k) * 16 + j];
        acc = fmaxf(acc, 0.0f);
        hdnw_lds[l * 16 + j] = acc * att_w2[j];
    }
    __syncthreads();

    if (tid < 64) {
        float s = -3.0e38f;
        if (tid < LL) {
            s = att_b2[0];
            for (int j = 0; j < 16; ++j) s += hdnw_lds[tid * 16 + j];
            if (mask[b * LL + tid] > 0.0f) s = -1.0e9f;
        }
        float mx = s;
        for (int off = 16; off >= 1; off >>= 1) mx = fmaxf(mx, __shfl_xor(mx, off));
        float ex = (tid < LL) ? __expf(s - mx) : 0.0f;
        float sum = ex;
        for (int off = 16; off >= 1; off >>= 1) sum += __shfl_xor(sum, off);
        if (tid < LL) wt_lds[tid] = ex / sum;
    }
    __syncthreads();

    if (tid < DD) {
        float g = 0.0f;
        #pragma unroll 4
        for (int l = 0; l < LL; ++l) g += wt_lds[l] * mem_lds[l * 129 + tid];
        float me = g + mash_lds[tid];
        float sv = svc_lds[tid];
        new_lds[tid]          = me * sv;
        new_lds[DD + tid]     = me;
        new_lds[2 * DD + tid] = sv;
    }
    __syncthreads();

    if (tid < 8) {
        float acc = pred_b1[tid];
        for (int k = 0; k < 3 * DD; ++k) acc += new_lds[k] * pred_w1[k * 8 + tid];
        acc = fmaxf(acc, 0.0f);
        hp_lds[tid] = acc * pred_w2[tid];
    }
    __syncthreads();

    if (tid == 0) {
        float z = pred_b2[0];
        for (int j = 0; j < 8; ++j) z += hp_lds[j];
        out[b] = 1.0f / (1.0f + __expf(-z));
    }
}

// ---------------------------------------------------------------------------
extern "C" void kernel_launch(void* const* d_in, const int* in_sizes, int n_in,
                              void* d_out, int out_size, void* d_ws, size_t ws_size,
                              hipStream_t stream) {
    const int*   mashup_inputs  = (const int*)  d_in[0];
    const int*   service_inputs = (const int*)  d_in[1];
    const int*   member_masked  = (const int*)  d_in[2];
    const float* mask           = (const float*)d_in[3];
    const int*   adj_rows       = (const int*)  d_in[4];
    const int*   adj_cols       = (const int*)  d_in[5];
    const float* adj_vals       = (const float*)d_in[6];
    const int*   A_rows         = (const int*)  d_in[7];
    const int*   A_cols         = (const int*)  d_in[8];
    const float* A_vals         = (const float*)d_in[9];
    const float* d_inv          = (const float*)d_in[10];
    const float* user_tbl       = (const float*)d_in[11];
    const float* service_tbl    = (const float*)d_in[12];
    const float* mashup_tbl     = (const float*)d_in[13];
    const float* att_w1         = (const float*)d_in[14];
    const float* att_b1         = (const float*)d_in[15];
    const float* att_w2         = (const float*)d_in[16];
    const float* att_b2         = (const float*)d_in[17];
    const float* pred_w1        = (const float*)d_in[18];
    const float* pred_b1        = (const float*)d_in[19];
    const float* pred_w2        = (const float*)d_in[20];
    const float* pred_b2        = (const float*)d_in[21];

    const int E_ui = in_sizes[4];
    const int E_mm = in_sizes[7];
    const int B    = in_sizes[0];

    const int N_UI2  = NBUK_UI * NCH;              // 400128
    const int N_MM2  = NBUK_MM * NCH;              // 120064
    const int NB_UI  = (N_UI2 + 1023) / 1024;      // 391
    const int NB_MM  = (N_MM2 + 1023) / 1024;      // 118
    const int csz_ui = (E_ui + NCH - 1) / NCH;
    const int csz_mm = (E_mm + NCH - 1) / NCH;

    // ---- workspace layout (UI and MM regions fully disjoint) ----
    uint2*   cvA_ui  = (uint2*)d_ws;                           // E_ui
    uint2*   cvA_mm  = cvA_ui + E_ui;                          // E_mm
    uint2*   cvB_ui  = cvA_mm + E_mm;                          // E_ui
    uint2*   cvB_mm  = cvB_ui + E_ui;                          // E_mm
    int*     h_ui    = (int*)(cvB_mm + E_mm);                  // N_UI2
    int*     s_ui    = h_ui + N_UI2;                           // N_UI2+1 (+pad)
    int*     h_mm    = s_ui + N_UI2 + 4;                       // N_MM2
    int*     s_mm    = h_mm + N_MM2;                           // N_MM2+1 (+pad)
    int*     bs_ui   = s_mm + N_MM2 + 4;                       // 512
    int*     bs_mm   = bs_ui + 512;                            // 128
    int*     rp_ui   = bs_mm + 128;                            // UIN_+1 (+pad)
    int*     rp_mm   = rp_ui + UIN_ + 4;                       // NM_+1 (+pad)
    uint32*  ui_bf   = (uint32*)(rp_mm + NM_ + 4);             // UIN*64  (bf16 pairs)
    uint32*  mash_bf = ui_bf + (size_t)UIN_ * 64;              // NM*64
    uint32*  h2      = mash_bf + (size_t)NM_ * 64;             // UIN*64  (ui_final, bf16)
    uint32*  m2      = h2 + (size_t)UIN_ * 64;                 // NM*64   (mash_final, bf16)
    uchar_t* ui_f8   = (uchar_t*)(m2 + (size_t)NM_ * 64);      // UIN*128 (scaled fp8)
    uchar_t* h1_f8   = ui_f8 + (size_t)UIN_ * DD;              // UIN*128
    uchar_t* mash_f8 = h1_f8 + (size_t)UIN_ * DD;              // NM*128
    uchar_t* m1_f8   = mash_f8 + (size_t)NM_ * DD;             // NM*128

    // ---- 1: table conversion (bf16 + scaled fp8, both tables) ----
    convert_fused<<<2048, 256, 0, stream>>>(user_tbl, service_tbl, mashup_tbl,
                                            ui_bf, (ushort_t*)ui_f8,
                                            mash_bf, (ushort_t*)mash_f8);

    // ---- 2-6: fused edge build (hist -> scan -> scatter -> sort) ----
    hist_fused<<<2 * NCH, 1024, 0, stream>>>(adj_rows, E_ui, csz_ui, h_ui,
                                             A_rows, E_mm, csz_mm, h_mm);
    scan_blocksum_fused<<<NB_UI + NB_MM, 256, 0, stream>>>(h_ui, N_UI2, bs_ui, NB_UI,
                                                           h_mm, N_MM2, bs_mm);
    scan_final_fused<<<NB_UI + NB_MM, 256, 0, stream>>>(h_ui, N_UI2, bs_ui, NB_UI, s_ui,
                                                        h_mm, N_MM2, bs_mm, s_mm);
    scatter_fused<<<2 * NCH, 1024, 0, stream>>>(
        adj_rows, adj_cols, adj_vals, s_ui, E_ui, csz_ui, cvA_ui,
        A_rows, A_cols, A_vals, s_mm, E_mm, csz_mm, cvA_mm);
    sort_fused<<<NBUK_UI + NBUK_MM, 256, 0, stream>>>(
        cvA_ui, s_ui, cvB_ui, rp_ui,
        cvA_mm, s_mm, cvB_mm, rp_mm);

    // ---- 7-10: propagation layers (unfused: per-graph L2 purity) ----
    const int ui_blocks = (UIN_ + 3) / 4;   // 25000
    const int mm_blocks = (NM_ + 3) / 4;    // 7500
    pull_mm_l1<<<mm_blocks, 256, 0, stream>>>(rp_mm, cvB_mm, mash_f8, d_inv, m1_f8);
    pull_ui_l1<<<ui_blocks, 256, 0, stream>>>(rp_ui, cvB_ui, ui_f8, h1_f8);
    pull_mm_l2<<<mm_blocks, 256, 0, stream>>>(rp_mm, cvB_mm, m1_f8, d_inv, mash_bf, m2);
    pull_ui_l2<<<ui_blocks, 256, 0, stream>>>(rp_ui, cvB_ui, h1_f8, ui_bf, h2);

    // ---- 11: attention + prediction tail ----
    attn_pred_kernel<<<B, 512, 0, stream>>>(
        mashup_inputs, service_inputs, member_masked, mask,
        h2, m2,
        att_w1, att_b1, att_w2, att_b2,
        pred_w1, pred_b1, pred_w2, pred_b2,
        (float*)d_out);
}

// Round 13
// 245.372 us; speedup vs baseline: 1.3978x; 1.0436x over previous
//
#include <hip/hip_runtime.h>
#include <climits>

#define NU_ 80000
#define NS_ 20000
#define NM_ 30000
#define UIN_ (NU_ + NS_)
#define DD 128
#define LL 32
#define RPB 64                                   // rows per bucket
#define NCH 256                                  // chunks per graph
#define NBUK_UI ((UIN_ + RPB - 1) / RPB)         // 1563
#define NBUK_MM ((NM_  + RPB - 1) / RPB)         // 469
#define NCONV 512                                // convert-role blocks in fused k1

#define F8_SCALE 512.0f
#define F8_INV   (1.0f / 512.0f)

typedef unsigned int   uint32;
typedef unsigned short ushort_t;
typedef unsigned char  uchar_t;
typedef float f32x2 __attribute__((ext_vector_type(2)));

__device__ __forceinline__ float bflo(uint32 u) { return __uint_as_float(u << 16); }
__device__ __forceinline__ float bfhi(uint32 u) { return __uint_as_float(u & 0xffff0000u); }
__device__ __forceinline__ uint32 f2bf(float f) {
    uint32 u = __float_as_uint(f);
    return (u + 0x7fffu + ((u >> 16) & 1u)) >> 16;   // RNE
}
__device__ __forceinline__ uint32 pack2bf(float lo, float hi) {
    return f2bf(lo) | (f2bf(hi) << 16);
}

// ---- OCP e4m3fn encode/decode (HW converts on gfx950, SW fallback) --------
__device__ __forceinline__ float dec1_f8(uint32 b) {
    uint32 em = b & 0x7fu;
    uint32 s  = (b & 0x80u) << 24;
    float vn = __uint_as_float(s | (((em >> 3) + 120u) << 23) | ((em & 7u) << 20));
    float vd = (float)(int)em * 0.001953125f;
    vd = (b & 0x80u) ? -vd : vd;
    return (em >= 8u) ? vn : vd;
}
__device__ __forceinline__ uint32 enc1_f8(float f) {
    uint32 u = __float_as_uint(f);
    uint32 s = (u >> 31) << 7;
    float a = fabsf(f);
    if (a >= 448.0f) return s | 0x7Eu;
    if (a < 0.015625f) {
        int m = (int)(a * 512.0f + 0.5f);
        return s | (uint32)m;
    }
    uint32 au = u & 0x7fffffffu;
    au += 0x7FFFFu + ((au >> 20) & 1u);
    uint32 em = (((au >> 23) - 120u) << 3) | ((au >> 20) & 7u);
    if (em >= 0x7Fu) em = 0x7Eu;
    return s | em;
}
__device__ __forceinline__ f32x2 dec2_f8(uint32 u) {   // bytes 0,1
#if __has_builtin(__builtin_amdgcn_cvt_pk_f32_fp8)
    return __builtin_amdgcn_cvt_pk_f32_fp8(u, false);
#else
    f32x2 r; r.x = dec1_f8(u & 0xffu); r.y = dec1_f8((u >> 8) & 0xffu); return r;
#endif
}
__device__ __forceinline__ f32x2 dec2_f8_hi(uint32 u) { // bytes 2,3
#if __has_builtin(__builtin_amdgcn_cvt_pk_f32_fp8)
    return __builtin_amdgcn_cvt_pk_f32_fp8(u, true);
#else
    f32x2 r; r.x = dec1_f8((u >> 16) & 0xffu); r.y = dec1_f8(u >> 24); return r;
#endif
}
__device__ __forceinline__ uint32 pack2f8(float lo, float hi) {
#if __has_builtin(__builtin_amdgcn_cvt_pk_fp8_f32)
    return (uint32)__builtin_amdgcn_cvt_pk_fp8_f32(lo, hi, 0, false) & 0xFFFFu;
#else
    return enc1_f8(lo) | (enc1_f8(hi) << 8);
#endif
}

// ---------------------------------------------------------------------------
// Fused stage 1: blocks [0,NCH) UI hist, [NCH,2NCH) MM hist,
// [2NCH, 2NCH+NCONV) table conversion (independent; overlaps hist).
// Edge reads int4-vectorized: thread owns 4 consecutive edges (csz % 4 == 0).
// ---------------------------------------------------------------------------
__global__ __launch_bounds__(1024) void convert_hist_fused(
    const int* __restrict__ rows_ui, int E_ui, int csz_ui, int* __restrict__ h_ui,
    const int* __restrict__ rows_mm, int E_mm, int csz_mm, int* __restrict__ h_mm,
    const float* __restrict__ user_tbl, const float* __restrict__ service_tbl,
    const float* __restrict__ mashup_tbl,
    uint32* __restrict__ ui_bf, ushort_t* __restrict__ ui_f8,
    uint32* __restrict__ mash_bf, ushort_t* __restrict__ mash_f8) {
    __shared__ int hist[NBUK_UI];
    const int bid = blockIdx.x;
    if (bid >= 2 * NCH) {   // ---- convert role ----
        const size_t P_UI = (size_t)UIN_ * 64;
        const size_t P_MM = (size_t)NM_ * 64;
        const size_t SPLIT = (size_t)NU_ * DD;
        size_t stride = (size_t)NCONV * 1024;
        for (size_t i = (size_t)(bid - 2 * NCH) * 1024 + threadIdx.x;
             i < P_UI + P_MM; i += stride) {
            if (i < P_UI) {
                size_t e = i * 2;
                const float* s = (e < SPLIT) ? (user_tbl + e) : (service_tbl + (e - SPLIT));
                float2 v = *reinterpret_cast<const float2*>(s);
                ui_bf[i] = pack2bf(v.x, v.y);
                ui_f8[i] = (ushort_t)pack2f8(v.x * F8_SCALE, v.y * F8_SCALE);
            } else {
                size_t j = i - P_UI;
                float2 v = *reinterpret_cast<const float2*>(mashup_tbl + j * 2);
                mash_bf[j] = pack2bf(v.x, v.y);
                mash_f8[j] = (ushort_t)pack2f8(v.x * F8_SCALE, v.y * F8_SCALE);
            }
        }
        return;
    }
    // ---- hist role ----
    const int* rows; int E, csz, nbuk, c; int* h;
    if (bid < NCH) { rows = rows_ui; E = E_ui; csz = csz_ui; h = h_ui; nbuk = NBUK_UI; c = bid; }
    else           { rows = rows_mm; E = E_mm; csz = csz_mm; h = h_mm; nbuk = NBUK_MM; c = bid - NCH; }
    for (int i = threadIdx.x; i < nbuk; i += 1024) hist[i] = 0;
    __syncthreads();
    const int lo = c * csz, hi = min(lo + csz, E);
    int i = lo + threadIdx.x * 4;
    for (; i + 3 < hi; i += 4096) {
        int4 r4 = *reinterpret_cast<const int4*>(rows + i);
        atomicAdd(&hist[r4.x >> 6], 1);
        atomicAdd(&hist[r4.y >> 6], 1);
        atomicAdd(&hist[r4.z >> 6], 1);
        atomicAdd(&hist[r4.w >> 6], 1);
    }
    if (i < hi) {
        for (int j = i; j < hi; ++j) atomicAdd(&hist[rows[j] >> 6], 1);
    }
    __syncthreads();
    for (int b = threadIdx.x; b < nbuk; b += 1024)
        h[b * NCH + c] = hist[b];
}

// ---------------------------------------------------------------------------
// Stage 2 (fused): multi-block exclusive scan over both histogram arrays.
// ---------------------------------------------------------------------------
__global__ __launch_bounds__(256) void scan_blocksum_fused(
    const int* __restrict__ h_ui, int n_ui, int* __restrict__ bs_ui, int nb_ui,
    const int* __restrict__ h_mm, int n_mm, int* __restrict__ bs_mm) {
    __shared__ int red[256];
    const int* cnt; int n, b; int* bsum;
    if ((int)blockIdx.x < nb_ui) { cnt = h_ui; n = n_ui; bsum = bs_ui; b = blockIdx.x; }
    else                         { cnt = h_mm; n = n_mm; bsum = bs_mm; b = blockIdx.x - nb_ui; }
    int base = b * 1024 + threadIdx.x * 4;
    int s = 0;
    if (base + 3 < n) {
        int4 v = *reinterpret_cast<const int4*>(cnt + base);
        s = v.x + v.y + v.z + v.w;
    } else {
        for (int i = base; i < n && i < base + 4; ++i) s += cnt[i];
    }
    red[threadIdx.x] = s;
    __syncthreads();
    for (int off = 128; off >= 1; off >>= 1) {
        if (threadIdx.x < off) red[threadIdx.x] += red[threadIdx.x + off];
        __syncthreads();
    }
    if (threadIdx.x == 0) bsum[b] = red[0];
}

__global__ __launch_bounds__(256) void scan_final_fused(
    int* __restrict__ h_ui, int n_ui, const int* __restrict__ bs_ui, int nb_ui,
    int* __restrict__ s_ui,
    int* __restrict__ h_mm, int n_mm, const int* __restrict__ bs_mm,
    int* __restrict__ s_mm) {
    __shared__ int lds[256];
    __shared__ int blk_off_s;
    const int tid = threadIdx.x;
    int* cnt; int n, b; const int* bsum; int* row_ptr;
    if ((int)blockIdx.x < nb_ui) { cnt = h_ui; n = n_ui; bsum = bs_ui; row_ptr = s_ui; b = blockIdx.x; }
    else                         { cnt = h_mm; n = n_mm; bsum = bs_mm; row_ptr = s_mm; b = blockIdx.x - nb_ui; }

    int s = 0;
    for (int j = tid; j < b; j += 256) s += bsum[j];
    lds[tid] = s;
    __syncthreads();
    for (int off = 128; off >= 1; off >>= 1) {
        if (tid < off) lds[tid] += lds[tid + off];
        __syncthreads();
    }
    if (tid == 0) blk_off_s = lds[0];
    __syncthreads();
    const int blk_off = blk_off_s;

    int base = b * 1024 + tid * 4;
    int c0 = 0, c1 = 0, c2 = 0, c3 = 0;
    if (base + 3 < n) {
        int4 v = *reinterpret_cast<const int4*>(cnt + base);
        c0 = v.x; c1 = v.y; c2 = v.z; c3 = v.w;
    } else {
        if (base     < n) c0 = cnt[base];
        if (base + 1 < n) c1 = cnt[base + 1];
        if (base + 2 < n) c2 = cnt[base + 2];
        if (base + 3 < n) c3 = cnt[base + 3];
    }
    int tsum = c0 + c1 + c2 + c3;
    __syncthreads();
    lds[tid] = tsum;
    __syncthreads();
    for (int off = 1; off < 256; off <<= 1) {
        int v = (tid >= off) ? lds[tid - off] : 0;
        __syncthreads();
        lds[tid] += v;
        __syncthreads();
    }
    int p0 = blk_off + ((tid > 0) ? lds[tid - 1] : 0);
    int p1 = p0 + c0, p2 = p1 + c1, p3 = p2 + c2, p4 = p3 + c3;

    if (base     < n) { row_ptr[base]     = p0; if (base     == n - 1) row_ptr[n] = p1; }
    if (base + 1 < n) { row_ptr[base + 1] = p1; if (base + 1 == n - 1) row_ptr[n] = p2; }
    if (base + 2 < n) { row_ptr[base + 2] = p2; if (base + 2 == n - 1) row_ptr[n] = p3; }
    if (base + 3 < n) { row_ptr[base + 3] = p3; if (base + 3 == n - 1) row_ptr[n] = p4; }
}

// ---------------------------------------------------------------------------
// Stage 3 (fused): per-chunk scatter into bucket-grouped cvA (per graph).
// int4-vectorized edge reads (thread owns 4 consecutive edges; csz % 4 == 0).
// Plain stores: temporally-local partial lines merge in L2 (round-11 lesson).
// ---------------------------------------------------------------------------
__global__ __launch_bounds__(1024) void scatter_fused(
    const int* __restrict__ rows_ui, const int* __restrict__ cols_ui,
    const float* __restrict__ vals_ui, const int* __restrict__ s_ui,
    int E_ui, int csz_ui, uint2* __restrict__ cvA_ui,
    const int* __restrict__ rows_mm, const int* __restrict__ cols_mm,
    const float* __restrict__ vals_mm, const int* __restrict__ s_mm,
    int E_mm, int csz_mm, uint2* __restrict__ cvA_mm) {
    __shared__ int cur[NBUK_UI];
    const int *rows, *cols; const float* vals; const int* s;
    int E, csz, nbuk, c; uint2* cvA;
    if ((int)blockIdx.x < NCH) {
        rows = rows_ui; cols = cols_ui; vals = vals_ui; s = s_ui;
        E = E_ui; csz = csz_ui; nbuk = NBUK_UI; c = blockIdx.x; cvA = cvA_ui;
    } else {
        rows = rows_mm; cols = cols_mm; vals = vals_mm; s = s_mm;
        E = E_mm; csz = csz_mm; nbuk = NBUK_MM; c = blockIdx.x - NCH; cvA = cvA_mm;
    }
    for (int b = threadIdx.x; b < nbuk; b += 1024) cur[b] = s[b * NCH + c];
    __syncthreads();
    const int lo = c * csz, hi = min(lo + csz, E);
    int i = lo + threadIdx.x * 4;
    for (; i + 3 < hi; i += 4096) {
        int4   r4 = *reinterpret_cast<const int4*>(rows + i);
        int4   q4 = *reinterpret_cast<const int4*>(cols + i);
        float4 v4 = *reinterpret_cast<const float4*>(vals + i);
        int p0 = atomicAdd(&cur[r4.x >> 6], 1);
        int p1 = atomicAdd(&cur[r4.y >> 6], 1);
        int p2 = atomicAdd(&cur[r4.z >> 6], 1);
        int p3 = atomicAdd(&cur[r4.w >> 6], 1);
        cvA[p0] = make_uint2((uint32)q4.x | ((uint32)(r4.x & 63) << 25), __float_as_uint(v4.x));
        cvA[p1] = make_uint2((uint32)q4.y | ((uint32)(r4.y & 63) << 25), __float_as_uint(v4.y));
        cvA[p2] = make_uint2((uint32)q4.z | ((uint32)(r4.z & 63) << 25), __float_as_uint(v4.z));
        cvA[p3] = make_uint2((uint32)q4.w | ((uint32)(r4.w & 63) << 25), __float_as_uint(v4.w));
    }
    if (i < hi) {
        for (int j = i; j < hi; ++j) {
            int r = rows[j];
            int pos = atomicAdd(&cur[r >> 6], 1);
            cvA[pos] = make_uint2((uint32)cols[j] | ((uint32)(r & 63) << 25),
                                  __float_as_uint(vals[j]));
        }
    }
}

// ---------------------------------------------------------------------------
// Stage 4 (fused): exact per-row sort within each bucket (both graphs).
// ---------------------------------------------------------------------------
__device__ __forceinline__ void sort_one_bucket(
    const uint2* __restrict__ cvA, const int* __restrict__ s,
    uint2* __restrict__ cvB, int* __restrict__ row_ptr, int nrows, int b,
    int* cnt, int* cur) {
    const int tid  = threadIdx.x;
    const int base = s[b * NCH];
    const int endb = s[(b + 1) * NCH];

    if (tid < RPB) cnt[tid] = 0;
    __syncthreads();
    for (int i = base + tid; i < endb; i += 256)
        atomicAdd(&cnt[cvA[i].x >> 25], 1);
    __syncthreads();
    if (tid < 64) {
        int c = cnt[tid];
        int x = c;
        #pragma unroll
        for (int off = 1; off < 64; off <<= 1) {
            int v = __shfl_up(x, off);
            if (tid >= off) x += v;
        }
        int excl = base + x - c;
        cur[tid] = excl;
        int grow = b * RPB + tid;
        if (grow <= nrows) row_ptr[grow] = excl;
    }
    __syncthreads();
    for (int i = base + tid; i < endb; i += 256) {
        uint2 e = cvA[i];
        int rl  = (int)(e.x >> 25);
        int pos = atomicAdd(&cur[rl], 1);
        cvB[pos] = make_uint2(e.x & 0x1FFFFFFu, e.y);
    }
}

__global__ __launch_bounds__(256) void sort_fused(
    const uint2* __restrict__ cvA_ui, const int* __restrict__ s_ui,
    uint2* __restrict__ cvB_ui, int* __restrict__ rp_ui,
    const uint2* __restrict__ cvA_mm, const int* __restrict__ s_mm,
    uint2* __restrict__ cvB_mm, int* __restrict__ rp_mm) {
    __shared__ int cnt[RPB];
    __shared__ int cur[RPB];
    if ((int)blockIdx.x < NBUK_UI)
        sort_one_bucket(cvA_ui, s_ui, cvB_ui, rp_ui, UIN_, blockIdx.x, cnt, cur);
    else
        sort_one_bucket(cvA_mm, s_mm, cvB_mm, rp_mm, NM_, blockIdx.x - NBUK_UI, cnt, cur);
}

// ---------------------------------------------------------------------------
// Pull SpMM row body — quarter-wave edges, 2-deep unroll (round-9/12 proven).
// Lane ql owns dims 8*ql..8*ql+7 (uint2 = 8 fp8 bytes). 8 edges in flight.
// Epilogue: shfl_xor(16,32) cross-quarter reduce, lanes 0-15 write.
// MODE bit0: d_inv scale. MODE bit1: bf16 combine out; else fp8 (scaled) out.
// ---------------------------------------------------------------------------
template <int MODE>
__device__ __forceinline__ void pull_row(
    const int wid, const int lane,
    const int* __restrict__ row_ptr, const uint2* __restrict__ cv,
    const uchar_t* __restrict__ x, const float* __restrict__ d_inv,
    const uint32* __restrict__ orig_bf, const uchar_t* __restrict__ hprev_f8,
    void* __restrict__ out)
{
    const int q    = lane >> 4;
    const int ql   = lane & 15;
    const int beg  = row_ptr[wid];
    const int end  = row_ptr[wid + 1];
    const int boff = ql << 3;

    float a0 = 0.f, a1 = 0.f, a2 = 0.f, a3 = 0.f;
    float a4 = 0.f, a5 = 0.f, a6 = 0.f, a7 = 0.f;

    int e = beg + q;
    for (; e + 4 < end; e += 8) {
        uint2 pa = cv[e];
        uint2 pb = cv[e + 4];
        uint2 ga = *reinterpret_cast<const uint2*>(x + (((size_t)pa.x) << 7) + boff);
        uint2 gb = *reinterpret_cast<const uint2*>(x + (((size_t)pb.x) << 7) + boff);
        float va = __uint_as_float(pa.y);
        float vb = __uint_as_float(pb.y);
        f32x2 d0 = dec2_f8(ga.x), d1 = dec2_f8_hi(ga.x);
        f32x2 d2 = dec2_f8(ga.y), d3 = dec2_f8_hi(ga.y);
        a0 += va * d0.x; a1 += va * d0.y; a2 += va * d1.x; a3 += va * d1.y;
        a4 += va * d2.x; a5 += va * d2.y; a6 += va * d3.x; a7 += va * d3.y;
        f32x2 e0 = dec2_f8(gb.x), e1 = dec2_f8_hi(gb.x);
        f32x2 e2 = dec2_f8(gb.y), e3 = dec2_f8_hi(gb.y);
        a0 += vb * e0.x; a1 += vb * e0.y; a2 += vb * e1.x; a3 += vb * e1.y;
        a4 += vb * e2.x; a5 += vb * e2.y; a6 += vb * e3.x; a7 += vb * e3.y;
    }
    if (e < end) {
        uint2 pa = cv[e];
        uint2 ga = *reinterpret_cast<const uint2*>(x + (((size_t)pa.x) << 7) + boff);
        float va = __uint_as_float(pa.y);
        f32x2 d0 = dec2_f8(ga.x), d1 = dec2_f8_hi(ga.x);
        f32x2 d2 = dec2_f8(ga.y), d3 = dec2_f8_hi(ga.y);
        a0 += va * d0.x; a1 += va * d0.y; a2 += va * d1.x; a3 += va * d1.y;
        a4 += va * d2.x; a5 += va * d2.y; a6 += va * d3.x; a7 += va * d3.y;
    }

    a0 += __shfl_xor(a0, 16); a0 += __shfl_xor(a0, 32);
    a1 += __shfl_xor(a1, 16); a1 += __shfl_xor(a1, 32);
    a2 += __shfl_xor(a2, 16); a2 += __shfl_xor(a2, 32);
    a3 += __shfl_xor(a3, 16); a3 += __shfl_xor(a3, 32);
    a4 += __shfl_xor(a4, 16); a4 += __shfl_xor(a4, 32);
    a5 += __shfl_xor(a5, 16); a5 += __shfl_xor(a5, 32);
    a6 += __shfl_xor(a6, 16); a6 += __shfl_xor(a6, 32);
    a7 += __shfl_xor(a7, 16); a7 += __shfl_xor(a7, 32);

    if (lane < 16) {
        if (MODE & 1) {
            float s = d_inv[wid];
            a0 *= s; a1 *= s; a2 *= s; a3 *= s;
            a4 *= s; a5 *= s; a6 *= s; a7 *= s;
        }
        if (MODE & 2) {
            const float inv3 = 1.0f / 3.0f;
            uint4 o = *reinterpret_cast<const uint4*>(orig_bf + (size_t)wid * 64 + (ql << 2));
            uint2 hp = *reinterpret_cast<const uint2*>(hprev_f8 + (((size_t)wid) << 7) + boff);
            f32x2 h0 = dec2_f8(hp.x), h1 = dec2_f8_hi(hp.x);
            f32x2 h2 = dec2_f8(hp.y), h3 = dec2_f8_hi(hp.y);
            uint4 r;
            r.x = pack2bf((bflo(o.x) + (h0.x + a0) * F8_INV) * inv3,
                          (bfhi(o.x) + (h0.y + a1) * F8_INV) * inv3);
            r.y = pack2bf((bflo(o.y) + (h1.x + a2) * F8_INV) * inv3,
                          (bfhi(o.y) + (h1.y + a3) * F8_INV) * inv3);
            r.z = pack2bf((bflo(o.z) + (h2.x + a4) * F8_INV) * inv3,
                          (bfhi(o.z) + (h2.y + a5) * F8_INV) * inv3);
            r.w = pack2bf((bflo(o.w) + (h3.x + a6) * F8_INV) * inv3,
                          (bfhi(o.w) + (h3.y + a7) * F8_INV) * inv3);
            *reinterpret_cast<uint4*>(reinterpret_cast<uint32*>(out) + (size_t)wid * 64 + (ql << 2)) = r;
        } else {
            uint2 r;
            r.x = pack2f8(a0, a1) | (pack2f8(a2, a3) << 16);
            r.y = pack2f8(a4, a5) | (pack2f8(a6, a7) << 16);
            *reinterpret_cast<uint2*>((uchar_t*)out + (((size_t)wid) << 7) + boff) = r;
        }
    }
}

// ---- unfused pull kernels (per-graph L2 purity; round-10 lesson) ----------
__global__ __launch_bounds__(256) void pull_ui_l1(
    const int* __restrict__ rp, const uint2* __restrict__ cv,
    const uchar_t* __restrict__ x, uchar_t* __restrict__ out) {
    const int lane = threadIdx.x & 63;
    int wid = blockIdx.x * 4 + (threadIdx.x >> 6);
    if (wid < UIN_) pull_row<0>(wid, lane, rp, cv, x, nullptr, nullptr, nullptr, out);
}
__global__ __launch_bounds__(256) void pull_mm_l1(
    const int* __restrict__ rp, const uint2* __restrict__ cv,
    const uchar_t* __restrict__ x, const float* __restrict__ d_inv,
    uchar_t* __restrict__ out) {
    const int lane = threadIdx.x & 63;
    int wid = blockIdx.x * 4 + (threadIdx.x >> 6);
    if (wid < NM_) pull_row<1>(wid, lane, rp, cv, x, d_inv, nullptr, nullptr, out);
}
__global__ __launch_bounds__(256) void pull_ui_l2(
    const int* __restrict__ rp, const uint2* __restrict__ cv,
    const uchar_t* __restrict__ h1, const uint32* __restrict__ orig_bf,
    uint32* __restrict__ out) {
    const int lane = threadIdx.x & 63;
    int wid = blockIdx.x * 4 + (threadIdx.x >> 6);
    if (wid < UIN_) pull_row<2>(wid, lane, rp, cv, h1, nullptr, orig_bf, h1, out);
}
__global__ __launch_bounds__(256) void pull_mm_l2(
    const int* __restrict__ rp, const uint2* __restrict__ cv,
    const uchar_t* __restrict__ m1, const float* __restrict__ d_inv,
    const uint32* __restrict__ orig_bf, uint32* __restrict__ out) {
    const int lane = threadIdx.x & 63;
    int wid = blockIdx.x * 4 + (threadIdx.x >> 6);
    if (wid < NM_) pull_row<3>(wid, lane, rp, cv, m1, d_inv, orig_bf, m1, out);
}

// ---------------------------------------------------------------------------
// Attention + prediction tail: one block (512 threads) per batch element.
// ---------------------------------------------------------------------------
__global__ __launch_bounds__(512) void attn_pred_kernel(
    const int* __restrict__ mashup_inputs, const int* __restrict__ service_inputs,
    const int* __restrict__ member_masked, const float* __restrict__ mask,
    const uint32* __restrict__ ui_final, const uint32* __restrict__ mash_final,
    const float* __restrict__ att_w1, const float* __restrict__ att_b1,
    const float* __restrict__ att_w2, const float* __restrict__ att_b2,
    const float* __restrict__ pred_w1, const float* __restrict__ pred_b1,
    const float* __restrict__ pred_w2, const float* __restrict__ pred_b2,
    float* __restrict__ out)
{
    const int b   = blockIdx.x;
    const int tid = threadIdx.x;

    __shared__ float mem_lds[LL * 129];
    __shared__ float svc_lds[DD];
    __shared__ float mash_lds[DD];
    __shared__ float w1_lds[2 * DD * 16];
    __shared__ float hdnw_lds[LL * 16];
    __shared__ float wt_lds[LL];
    __shared__ float new_lds[3 * DD];
    __shared__ float hp_lds[8];
    __shared__ int   midx[LL];

    if (tid < LL) midx[tid] = member_masked[b * LL + tid];
    for (int i = tid; i < 2 * DD * 16; i += 512) w1_lds[i] = att_w1[i];
    if (tid < 64) {
        int sidx = service_inputs[b];
        uint32 u = ui_final[(size_t)(NU_ + sidx) * 64 + tid];
        svc_lds[tid * 2]     = bflo(u);
        svc_lds[tid * 2 + 1] = bfhi(u);
    } else if (tid >= 448) {
        int t  = tid - 448;
        int mi = mashup_inputs[b];
        uint32 u = mash_final[(size_t)mi * 64 + t];
        mash_lds[t * 2]     = bflo(u);
        mash_lds[t * 2 + 1] = bfhi(u);
    }
    __syncthreads();

    for (int i = tid; i < LL * 64; i += 512) {
        int l = i >> 6, dp = (i & 63) * 2;
        uint32 u = ui_final[(size_t)midx[l] * 64 + (i & 63)];
        mem_lds[l * 129 + dp]     = bflo(u);
        mem_lds[l * 129 + dp + 1] = bfhi(u);
    }
    __syncthreads();

    {
        int l = tid >> 4, j = tid & 15;
        float acc = att_b1[j];
        const float* m = &mem_lds[l * 129];
        #pragma unroll 4
        for (int k = 0; k < DD; ++k) acc += m[k] * w1_lds[k * 16 + j];
        #pragma unroll 4
        for (int k = 0; k < DD; ++k) acc += svc_lds[k] * w1_lds[(DD + k) * 16 + j];
        acc = fmaxf(acc, 0.0f);
        hdnw_lds[l * 16 + j] = acc * att_w2[j];
    }
    __syncthreads();

    if (tid < 64) {
        float s = -3.0e38f;
        if (tid < LL) {
            s = att_b2[0];
            for (int j = 0; j < 16; ++j) s += hdnw_lds[tid * 16 + j];
            if (mask[b * LL + tid] > 0.0f) s = -1.0e9f;
        }
        float mx = s;
        for (int off = 16; off >= 1; off >>= 1) mx = fmaxf(mx, __shfl_xor(mx, off));
        float ex = (tid < LL) ? __expf(s - mx) : 0.0f;
        float sum = ex;
        for (int off = 16; off >= 1; off >>= 1) sum += __shfl_xor(sum, off);
        if (tid < LL) wt_lds[tid] = ex / sum;
    }
    __syncthreads();

    if (tid < DD) {
        float g = 0.0f;
        #pragma unroll 4
        for (int l = 0; l < LL; ++l) g += wt_lds[l] * mem_lds[l * 129 + tid];
        float me = g + mash_lds[tid];
        float sv = svc_lds[tid];
        new_lds[tid]          = me * sv;
        new_lds[DD + tid]     = me;
        new_lds[2 * DD + tid] = sv;
    }
    __syncthreads();

    if (tid < 8) {
        float acc = pred_b1[tid];
        for (int k = 0; k < 3 * DD; ++k) acc += new_lds[k] * pred_w1[k * 8 + tid];
        acc = fmaxf(acc, 0.0f);
        hp_lds[tid] = acc * pred_w2[tid];
    }
    __syncthreads();

    if (tid == 0) {
        float z = pred_b2[0];
        for (int j = 0; j < 8; ++j) z += hp_lds[j];
        out[b] = 1.0f / (1.0f + __expf(-z));
    }
}

// ---------------------------------------------------------------------------
extern "C" void kernel_launch(void* const* d_in, const int* in_sizes, int n_in,
                              void* d_out, int out_size, void* d_ws, size_t ws_size,
                              hipStream_t stream) {
    const int*   mashup_inputs  = (const int*)  d_in[0];
    const int*   service_inputs = (const int*)  d_in[1];
    const int*   member_masked  = (const int*)  d_in[2];
    const float* mask           = (const float*)d_in[3];
    const int*   adj_rows       = (const int*)  d_in[4];
    const int*   adj_cols       = (const int*)  d_in[5];
    const float* adj_vals       = (const float*)d_in[6];
    const int*   A_rows         = (const int*)  d_in[7];
    const int*   A_cols         = (const int*)  d_in[8];
    const float* A_vals         = (const float*)d_in[9];
    const float* d_inv          = (const float*)d_in[10];
    const float* user_tbl       = (const float*)d_in[11];
    const float* service_tbl    = (const float*)d_in[12];
    const float* mashup_tbl     = (const float*)d_in[13];
    const float* att_w1         = (const float*)d_in[14];
    const float* att_b1         = (const float*)d_in[15];
    const float* att_w2         = (const float*)d_in[16];
    const float* att_b2         = (const float*)d_in[17];
    const float* pred_w1        = (const float*)d_in[18];
    const float* pred_b1        = (const float*)d_in[19];
    const float* pred_w2        = (const float*)d_in[20];
    const float* pred_b2        = (const float*)d_in[21];

    const int E_ui = in_sizes[4];
    const int E_mm = in_sizes[7];
    const int B    = in_sizes[0];

    const int N_UI2  = NBUK_UI * NCH;              // 400128
    const int N_MM2  = NBUK_MM * NCH;              // 120064
    const int NB_UI  = (N_UI2 + 1023) / 1024;      // 391
    const int NB_MM  = (N_MM2 + 1023) / 1024;      // 118
    // chunk sizes rounded up to multiple of 4 -> 16B-aligned int4 edge reads
    const int csz_ui = (((E_ui + NCH - 1) / NCH) + 3) & ~3;
    const int csz_mm = (((E_mm + NCH - 1) / NCH) + 3) & ~3;

    // ---- workspace layout (UI and MM regions fully disjoint) ----
    uint2*   cvA_ui  = (uint2*)d_ws;                           // E_ui
    uint2*   cvA_mm  = cvA_ui + E_ui;                          // E_mm
    uint2*   cvB_ui  = cvA_mm + E_mm;                          // E_ui
    uint2*   cvB_mm  = cvB_ui + E_ui;                          // E_mm
    int*     h_ui    = (int*)(cvB_mm + E_mm);                  // N_UI2
    int*     s_ui    = h_ui + N_UI2;                           // N_UI2+1 (+pad)
    int*     h_mm    = s_ui + N_UI2 + 4;                       // N_MM2
    int*     s_mm    = h_mm + N_MM2;                           // N_MM2+1 (+pad)
    int*     bs_ui   = s_mm + N_MM2 + 4;                       // 512
    int*     bs_mm   = bs_ui + 512;                            // 128
    int*     rp_ui   = bs_mm + 128;                            // UIN_+1 (+pad)
    int*     rp_mm   = rp_ui + UIN_ + 4;                       // NM_+1 (+pad)
    uint32*  ui_bf   = (uint32*)(rp_mm + NM_ + 4);             // UIN*64  (bf16 pairs)
    uint32*  mash_bf = ui_bf + (size_t)UIN_ * 64;              // NM*64
    uint32*  h2      = mash_bf + (size_t)NM_ * 64;             // UIN*64  (ui_final, bf16)
    uint32*  m2      = h2 + (size_t)UIN_ * 64;                 // NM*64   (mash_final, bf16)
    uchar_t* ui_f8   = (uchar_t*)(m2 + (size_t)NM_ * 64);      // UIN*128 (scaled fp8)
    uchar_t* h1_f8   = ui_f8 + (size_t)UIN_ * DD;              // UIN*128
    uchar_t* mash_f8 = h1_f8 + (size_t)UIN_ * DD;              // NM*128
    uchar_t* m1_f8   = mash_f8 + (size_t)NM_ * DD;             // NM*128

    // ---- 1: fused conversion + bucket histograms ----
    convert_hist_fused<<<2 * NCH + NCONV, 1024, 0, stream>>>(
        adj_rows, E_ui, csz_ui, h_ui,
        A_rows, E_mm, csz_mm, h_mm,
        user_tbl, service_tbl, mashup_tbl,
        ui_bf, (ushort_t*)ui_f8, mash_bf, (ushort_t*)mash_f8);

    // ---- 2-5: scan -> scatter -> sort ----
    scan_blocksum_fused<<<NB_UI + NB_MM, 256, 0, stream>>>(h_ui, N_UI2, bs_ui, NB_UI,
                                                           h_mm, N_MM2, bs_mm);
    scan_final_fused<<<NB_UI + NB_MM, 256, 0, stream>>>(h_ui, N_UI2, bs_ui, NB_UI, s_ui,
                                                        h_mm, N_MM2, bs_mm, s_mm);
    scatter_fused<<<2 * NCH, 1024, 0, stream>>>(
        adj_rows, adj_cols, adj_vals, s_ui, E_ui, csz_ui, cvA_ui,
        A_rows, A_cols, A_vals, s_mm, E_mm, csz_mm, cvA_mm);
    sort_fused<<<NBUK_UI + NBUK_MM, 256, 0, stream>>>(
        cvA_ui, s_ui, cvB_ui, rp_ui,
        cvA_mm, s_mm, cvB_mm, rp_mm);

    // ---- 6-9: propagation layers (unfused: per-graph L2 purity) ----
    const int ui_blocks = (UIN_ + 3) / 4;   // 25000
    const int mm_blocks = (NM_ + 3) / 4;    // 7500
    pull_mm_l1<<<mm_blocks, 256, 0, stream>>>(rp_mm, cvB_mm, mash_f8, d_inv, m1_f8);
    pull_ui_l1<<<ui_blocks, 256, 0, stream>>>(rp_ui, cvB_ui, ui_f8, h1_f8);
    pull_mm_l2<<<mm_blocks, 256, 0, stream>>>(rp_mm, cvB_mm, m1_f8, d_inv, mash_bf, m2);
    pull_ui_l2<<<ui_blocks, 256, 0, stream>>>(rp_ui, cvB_ui, h1_f8, ui_bf, h2);

    // ---- 10: attention + prediction tail ----
    attn_pred_kernel<<<B, 512, 0, stream>>>(
        mashup_inputs, service_inputs, member_masked, mask,
        h2, m2,
        att_w1, att_b1, att_w2, att_b2,
        pred_w1, pred_b1, pred_w2, pred_b2,
        (float*)d_out);
}